// Round 2
// baseline (3489.588 us; speedup 1.0000x reference)
//
#include <hip/hip_runtime.h>

#define NN 100000
#define NE 3200000
#define FIN 512
#define FH 64
#define FC 40
#define KRANK 1600000u   // E - int(E*0.5), 0-indexed ascending rank
#define NB1 98           // ceil(NN/1024)

// ---------------- degree count + edge-weight high-16 histogram ----------------
__global__ __launch_bounds__(256) void count_hist(const int* __restrict__ dstv,
                                                  const float* __restrict__ ew,
                                                  int* __restrict__ cnt,
                                                  unsigned* __restrict__ hist1) {
    int e = blockIdx.x * 256 + threadIdx.x;
    if (e >= NE) return;
    atomicAdd(&cnt[dstv[e]], 1);
    unsigned bits = __float_as_uint(ew[e]);
    atomicAdd(&hist1[bits >> 16], 1u);
}

// ---------------- prefix scan (3 kernels) ----------------
__global__ __launch_bounds__(1024) void scan1(const int* __restrict__ cnt,
                                              int* __restrict__ row_ptr,
                                              int* __restrict__ bsum,
                                              float* __restrict__ dis) {
    __shared__ int sc[1024];
    int tid = threadIdx.x;
    int i = blockIdx.x * 1024 + tid;
    int v = (i < NN) ? cnt[i] : 0;
    sc[tid] = v;
    __syncthreads();
    for (int off = 1; off < 1024; off <<= 1) {
        int t = (tid >= off) ? sc[tid - off] : 0;
        __syncthreads();
        sc[tid] += t;
        __syncthreads();
    }
    int incl = sc[tid];
    if (i < NN) {
        row_ptr[i + 1] = incl;                    // pre-offset inclusive scan
        dis[i] = rsqrtf((float)v + 1.0f);         // deg_inv_sqrt (with self loop)
    }
    if (tid == 1023) bsum[blockIdx.x] = incl;
}

__global__ __launch_bounds__(128) void scan2(const int* __restrict__ bsum,
                                             int* __restrict__ boff) {
    __shared__ int sc[128];
    int tid = threadIdx.x;
    int v = (tid < NB1) ? bsum[tid] : 0;
    sc[tid] = v;
    __syncthreads();
    for (int off = 1; off < 128; off <<= 1) {
        int t = (tid >= off) ? sc[tid - off] : 0;
        __syncthreads();
        sc[tid] += t;
        __syncthreads();
    }
    if (tid < NB1) boff[tid] = sc[tid] - v;       // exclusive block offsets
}

__global__ __launch_bounds__(1024) void scan3(const int* __restrict__ cnt,
                                              const int* __restrict__ boff,
                                              int* __restrict__ row_ptr,
                                              int* __restrict__ fill) {
    int i = blockIdx.x * 1024 + threadIdx.x;
    if (i >= NN) return;
    int incl = row_ptr[i + 1] + boff[blockIdx.x];
    row_ptr[i + 1] = incl;
    fill[i] = incl - cnt[i];                      // row start
    if (i == 0) row_ptr[0] = 0;
}

// ---------------- CSR fill ----------------
__global__ __launch_bounds__(256) void csr_fill(const int* __restrict__ srcv,
                                                const int* __restrict__ dstv,
                                                int* __restrict__ fill,
                                                int* __restrict__ csr_src) {
    int e = blockIdx.x * 256 + threadIdx.x;
    if (e >= NE) return;
    int p = atomicAdd(&fill[dstv[e]], 1);
    csr_src[p] = srcv[e];
}

// ---------------- radix-select: find bucket containing rank KRANK ----------------
__global__ __launch_bounds__(1024) void select_hi(const unsigned* __restrict__ hist,
                                                  int* __restrict__ sel_br) {
    __shared__ unsigned sc[1024];
    __shared__ unsigned runs;
    int tid = threadIdx.x;
    if (tid == 0) runs = 0;
    __syncthreads();
    for (int ch = 0; ch < 64; ++ch) {
        unsigned v = hist[ch * 1024 + tid];
        sc[tid] = v;
        __syncthreads();
        for (int off = 1; off < 1024; off <<= 1) {
            unsigned t = (tid >= off) ? sc[tid - off] : 0u;
            __syncthreads();
            sc[tid] += t;
            __syncthreads();
        }
        unsigned incl = sc[tid];
        unsigned base = runs;
        unsigned lo = base + incl - v, hi = base + incl;
        if (KRANK >= lo && KRANK < hi) {
            sel_br[0] = ch * 1024 + tid;
            sel_br[1] = (int)(KRANK - lo);
        }
        __syncthreads();
        if (tid == 1023) runs = base + incl;
        __syncthreads();
    }
}

__global__ __launch_bounds__(256) void hist_low(const float* __restrict__ ew,
                                                const int* __restrict__ sel_br,
                                                unsigned* __restrict__ hist2) {
    int e = blockIdx.x * 256 + threadIdx.x;
    if (e >= NE) return;
    unsigned bits = __float_as_uint(ew[e]);
    if ((int)(bits >> 16) == sel_br[0]) atomicAdd(&hist2[bits & 0xFFFFu], 1u);
}

__global__ __launch_bounds__(1024) void select_lo(const unsigned* __restrict__ hist2,
                                                  const int* __restrict__ sel_br,
                                                  float* __restrict__ thr) {
    __shared__ unsigned sc[1024];
    __shared__ unsigned runs;
    int tid = threadIdx.x;
    unsigned Kr = (unsigned)sel_br[1];
    unsigned bhi = (unsigned)sel_br[0];
    if (tid == 0) runs = 0;
    __syncthreads();
    for (int ch = 0; ch < 64; ++ch) {
        unsigned v = hist2[ch * 1024 + tid];
        sc[tid] = v;
        __syncthreads();
        for (int off = 1; off < 1024; off <<= 1) {
            unsigned t = (tid >= off) ? sc[tid - off] : 0u;
            __syncthreads();
            sc[tid] += t;
            __syncthreads();
        }
        unsigned incl = sc[tid];
        unsigned base = runs;
        unsigned lo = base + incl - v, hi = base + incl;
        if (Kr >= lo && Kr < hi) {
            unsigned bits = (bhi << 16) | (unsigned)(ch * 1024 + tid);
            thr[0] = __uint_as_float(bits);
        }
        __syncthreads();
        if (tid == 1023) runs = base + incl;
        __syncthreads();
    }
}

// ---------------- GEMM1: h = x @ w1  (100000x512 @ 512x64), fp32 ----------------
__global__ __launch_bounds__(256) void gemm1(const float* __restrict__ x,
                                             const float* __restrict__ w1,
                                             float* __restrict__ h) {
    __shared__ float xs[32 * 72];   // [kk][r], pad 72 keeps 16B align + bank-free frag reads
    __shared__ float wsb[32 * 64];  // [kk][c]
    int tid = threadIdx.x;
    int rowBase = blockIdx.x * 64;
    int tr = tid & 15, tc = tid >> 4;
    float acc[4][4] = {};
    for (int k0 = 0; k0 < FIN; k0 += 32) {
#pragma unroll
        for (int i = 0; i < 8; ++i) {
            int lin = tid + 256 * i;
            int r = lin >> 5, kk = lin & 31;
            int gr = rowBase + r;
            float v = (gr < NN) ? x[gr * FIN + k0 + kk] : 0.f;
            xs[kk * 72 + r] = v;
        }
#pragma unroll
        for (int i = 0; i < 8; ++i) {
            int lin = tid + 256 * i;
            int kk = lin >> 6, c = lin & 63;
            wsb[kk * 64 + c] = w1[(k0 + kk) * FH + c];
        }
        __syncthreads();
#pragma unroll
        for (int kk = 0; kk < 32; ++kk) {
            float4 xv = *(const float4*)&xs[kk * 72 + tr * 4];
            float4 wv = *(const float4*)&wsb[kk * 64 + tc * 4];
            float xa[4] = {xv.x, xv.y, xv.z, xv.w};
            float wa[4] = {wv.x, wv.y, wv.z, wv.w};
#pragma unroll
            for (int a = 0; a < 4; ++a)
#pragma unroll
                for (int b = 0; b < 4; ++b) acc[a][b] = fmaf(xa[a], wa[b], acc[a][b]);
        }
        __syncthreads();
    }
#pragma unroll
    for (int a = 0; a < 4; ++a) {
        int gr = rowBase + tr * 4 + a;
        if (gr < NN) {
            float4 o = make_float4(acc[a][0], acc[a][1], acc[a][2], acc[a][3]);
            *(float4*)&h[gr * FH + tc * 4] = o;
        }
    }
}

// ---------------- aggregate layer 1 (+bias+relu), wave per node ----------------
__global__ __launch_bounds__(256) void agg_relu1(const float* __restrict__ h,
                                                 const float* __restrict__ dis,
                                                 const int* __restrict__ row_ptr,
                                                 const int* __restrict__ csr_src,
                                                 const float* __restrict__ b1,
                                                 float* __restrict__ h1) {
    int wave = threadIdx.x >> 6, lane = threadIdx.x & 63;
    int n = blockIdx.x * 4 + wave;
    if (n >= NN) return;
    float dn = dis[n];
    float acc = h[n * FH + lane] * (dn * dn);
    int e0 = row_ptr[n], e1 = row_ptr[n + 1];
    for (int e = e0; e < e1; ++e) {
        int s = csr_src[e];
        acc += h[s * FH + lane] * (dis[s] * dn);
    }
    float v = acc + b1[lane];
    h1[n * FH + lane] = fmaxf(v, 0.f);
}

// ---------------- GEMM2: h2 = h1 @ w2  (100000x64 @ 64x40) ----------------
// NOTE: all 64 lanes must stay ACTIVE through every __shfl — ds_bpermute from
// an EXEC-masked lane is undefined on CDNA. Lanes >= FC compute a dummy
// column (cl=0) and simply don't store.
__global__ __launch_bounds__(256) void gemm2(const float* __restrict__ h1,
                                             const float* __restrict__ w2,
                                             float* __restrict__ h2) {
    __shared__ float w2s[FH * FC];
    int tid = threadIdx.x;
    for (int i = tid; i < FH * FC; i += 256) w2s[i] = w2[i];
    __syncthreads();
    int wave = tid >> 6, lane = tid & 63;
    int n = blockIdx.x * 4 + wave;
    if (n >= NN) return;
    float hv = h1[n * FH + lane];   // all 64 lanes valid
    int cl = (lane < FC) ? lane : 0;
    float acc = 0.f;
#pragma unroll
    for (int k = 0; k < FH; ++k) {
        float xk = __shfl(hv, k);            // fully-active wave
        acc = fmaf(xk, w2s[k * FC + cl], acc);
    }
    if (lane < FC) h2[n * FC + lane] = acc;
}

// ---------------- aggregate layer 2 + bias + x2 + rnorm + log_softmax ----------------
__global__ __launch_bounds__(256) void agg2_fused(const float* __restrict__ h2,
                                                  const float* __restrict__ dis,
                                                  const int* __restrict__ row_ptr,
                                                  const int* __restrict__ csr_src,
                                                  const float* __restrict__ b2,
                                                  float* __restrict__ x2,
                                                  float* __restrict__ rnorm,
                                                  float* __restrict__ outls) {
    int wave = threadIdx.x >> 6, lane = threadIdx.x & 63;
    int n = blockIdx.x * 4 + wave;
    if (n >= NN) return;
    bool act = lane < FC;
    float dn = dis[n];
    float acc = act ? h2[n * FC + lane] * (dn * dn) : 0.f;
    int e0 = row_ptr[n], e1 = row_ptr[n + 1];
    for (int e = e0; e < e1; ++e) {
        int s = csr_src[e];
        float nw = dis[s] * dn;
        if (act) acc += h2[s * FC + lane] * nw;
    }
    float x2v = act ? acc + b2[lane] : -3.4e38f;
    if (act) x2[n * FC + lane] = x2v;
    float m = x2v;
#pragma unroll
    for (int off = 32; off; off >>= 1) m = fmaxf(m, __shfl_xor(m, off));
    float ex = act ? expf(x2v - m) : 0.f;
    float sq = act ? x2v * x2v : 0.f;
#pragma unroll
    for (int off = 32; off; off >>= 1) {
        ex += __shfl_xor(ex, off);
        sq += __shfl_xor(sq, off);
    }
    if (act) outls[n * FC + lane] = x2v - m - logf(ex);
    if (lane == 0) rnorm[n] = fmaxf(sqrtf(sq), 1e-8f);
}

// ---------------- edge loss ----------------
__global__ __launch_bounds__(256) void loss_kernel(const int* __restrict__ srcv,
                                                   const int* __restrict__ dstv,
                                                   const float* __restrict__ ew,
                                                   const float* __restrict__ lu,
                                                   const float* __restrict__ x2,
                                                   const float* __restrict__ rnorm,
                                                   const float* __restrict__ thr,
                                                   double* __restrict__ acc) {
    int e = blockIdx.x * 256 + threadIdx.x;
    float term = 0.f;
    if (e < NE) {
        int s = srcv[e], d = dstv[e];
        const float4* a = (const float4*)x2 + s * 10;
        const float4* b = (const float4*)x2 + d * 10;
        float dot = 0.f;
#pragma unroll
        for (int i = 0; i < 10; ++i) {
            float4 av = a[i], bv = b[i];
            dot += av.x * bv.x + av.y * bv.y + av.z * bv.z + av.w * bv.w;
        }
        float cosv = dot / (rnorm[s] * rnorm[d]);
        float cs = 1.f - cosv;
        float w = ew[e];
        bool mk = (w >= thr[0]);
        float lp = mk ? cs : 1.f - cs;
        float le = mk ? w : 1.f - w;
        term = le * lp * lu[e];
    }
#pragma unroll
    for (int off = 32; off; off >>= 1) term += __shfl_down(term, off);
    __shared__ float ws4[4];
    int lane = threadIdx.x & 63, wid = threadIdx.x >> 6;
    if (lane == 0) ws4[wid] = term;
    __syncthreads();
    if (threadIdx.x == 0) {
        double s = (double)ws4[0] + (double)ws4[1] + (double)ws4[2] + (double)ws4[3];
        atomicAdd(acc, s);
    }
}

__global__ void finalize(const double* __restrict__ acc, float* __restrict__ out) {
    out[NN * FC] = (float)(acc[0] * (1.0 / (double)NE));
}

// ---------------- host launch ----------------
extern "C" void kernel_launch(void* const* d_in, const int* in_sizes, int n_in,
                              void* d_out, int out_size, void* d_ws, size_t ws_size,
                              hipStream_t stream) {
    const float* x  = (const float*)d_in[0];
    const int*   ei = (const int*)d_in[1];
    const float* ew = (const float*)d_in[2];
    const float* lu = (const float*)d_in[3];
    const float* w1 = (const float*)d_in[4];
    const float* b1 = (const float*)d_in[5];
    const float* w2 = (const float*)d_in[6];
    const float* b2 = (const float*)d_in[7];
    float* out = (float*)d_out;
    const int* srcv = ei;
    const int* dstv = ei + NE;

    char* ws = (char*)d_ws;
    size_t off = 0;
    auto alloc = [&](size_t bytes) -> void* {
        void* p = ws + off;
        off += (bytes + 255) & ~(size_t)255;
        return p;
    };
    float*    dis     = (float*)alloc((size_t)NN * 4);
    int*      cnt     = (int*)alloc((size_t)NN * 4);
    int*      row_ptr = (int*)alloc((size_t)(NN + 1) * 4);
    int*      fill    = (int*)alloc((size_t)NN * 4);
    int*      csr_src = (int*)alloc((size_t)NE * 4);
    float*    h       = (float*)alloc((size_t)NN * FH * 4);
    float*    h1      = (float*)alloc((size_t)NN * FH * 4);
    float*    h2      = (float*)alloc((size_t)NN * FC * 4);
    float*    x2      = (float*)alloc((size_t)NN * FC * 4);
    float*    rnorm   = (float*)alloc((size_t)NN * 4);
    unsigned* hist1   = (unsigned*)alloc((size_t)65536 * 4);
    unsigned* hist2   = (unsigned*)alloc((size_t)65536 * 4);
    int*      bsum    = (int*)alloc(128 * 4);
    int*      boff    = (int*)alloc(128 * 4);
    int*      sel     = (int*)alloc(256);
    float*    thr     = (float*)alloc(256);
    double*   accd    = (double*)alloc(256);

    hipMemsetAsync(cnt, 0, (size_t)NN * 4, stream);
    hipMemsetAsync(hist1, 0, (size_t)65536 * 4 * 2, stream);  // hist1+hist2 contiguous
    hipMemsetAsync(accd, 0, 8, stream);

    const int EB = (NE + 255) / 256;      // 12500
    const int NB4 = (NN + 3) / 4;         // 25000

    count_hist<<<EB, 256, 0, stream>>>(dstv, ew, cnt, hist1);
    scan1<<<NB1, 1024, 0, stream>>>(cnt, row_ptr, bsum, dis);
    scan2<<<1, 128, 0, stream>>>(bsum, boff);
    scan3<<<NB1, 1024, 0, stream>>>(cnt, boff, row_ptr, fill);
    csr_fill<<<EB, 256, 0, stream>>>(srcv, dstv, fill, csr_src);
    select_hi<<<1, 1024, 0, stream>>>(hist1, sel);
    hist_low<<<EB, 256, 0, stream>>>(ew, sel, hist2);
    select_lo<<<1, 1024, 0, stream>>>(hist2, sel, thr);
    gemm1<<<(NN + 63) / 64, 256, 0, stream>>>(x, w1, h);
    agg_relu1<<<NB4, 256, 0, stream>>>(h, dis, row_ptr, csr_src, b1, h1);
    gemm2<<<NB4, 256, 0, stream>>>(h1, w2, h2);
    agg2_fused<<<NB4, 256, 0, stream>>>(h2, dis, row_ptr, csr_src, b2, x2, rnorm, out);
    loss_kernel<<<EB, 256, 0, stream>>>(srcv, dstv, ew, lu, x2, rnorm, thr, accd);
    finalize<<<1, 1, 0, stream>>>(accd, out);
}

// Round 3
// 1916.885 us; speedup vs baseline: 1.8204x; 1.8204x over previous
//
#include <hip/hip_runtime.h>

#define NN 100000
#define NE 3200000
#define FIN 512
#define FH 64
#define FC 40
#define KRANK 1600000u   // E - int(E*0.5), 0-indexed ascending rank
#define NB1 98           // ceil(NN/1024)
#define HBLK 128         // blocks for hist passes (NE/HBLK = 25000 exactly)
#define HBINS 2048

// ---------------- degree count (spread atomics over 100k addresses) ----------------
__global__ __launch_bounds__(256) void deg_count(const int* __restrict__ dstv,
                                                 int* __restrict__ cnt) {
    int e = blockIdx.x * 256 + threadIdx.x;
    if (e >= NE) return;
    atomicAdd(&cnt[dstv[e]], 1);
}

// ---------------- LDS-privatized histogram pass (no global atomics) ----------------
// stage 0: bin = bits>>21            (top 11 bits)
// stage 1: match top-11, bin = (bits>>10)&0x7FF
// stage 2: match top-22, bin = bits&0x3FF
__global__ __launch_bounds__(256) void hist_pass(const float* __restrict__ ew,
                                                 const int* __restrict__ sel,
                                                 int stage,
                                                 unsigned* __restrict__ part) {
    __shared__ unsigned lh[4 * HBINS];   // one sub-histogram per wave
    int tid = threadIdx.x, blk = blockIdx.x;
    int wv = tid >> 6;
    for (int i = tid; i < 4 * HBINS; i += 256) lh[i] = 0u;
    __syncthreads();
    unsigned m1 = 0, m2 = 0;
    if (stage == 1) m1 = (unsigned)sel[0];
    if (stage == 2) m2 = ((unsigned)sel[0] << 11) | (unsigned)sel[2];
    int base = blk * (NE / HBLK);
    for (int t = tid; t < NE / HBLK; t += 256) {
        unsigned bits = __float_as_uint(ew[base + t]);
        if (stage == 0) {
            atomicAdd(&lh[wv * HBINS + (bits >> 21)], 1u);
        } else if (stage == 1) {
            if ((bits >> 21) == m1) atomicAdd(&lh[wv * HBINS + ((bits >> 10) & 0x7FFu)], 1u);
        } else {
            if ((bits >> 10) == m2) atomicAdd(&lh[wv * HBINS + (bits & 0x3FFu)], 1u);
        }
    }
    __syncthreads();
    for (int i = tid; i < HBINS; i += 256)
        part[blk * HBINS + i] = lh[i] + lh[HBINS + i] + lh[2 * HBINS + i] + lh[3 * HBINS + i];
}

// ---------------- reduce partials: hist[bin] = sum_p part[p][bin] ----------------
__global__ __launch_bounds__(256) void hist_reduce(const unsigned* __restrict__ part,
                                                   unsigned* __restrict__ hist) {
    int bin = blockIdx.x * 256 + threadIdx.x;   // grid 8 x 256 = 2048
    unsigned s = 0;
    for (int p = 0; p < HBLK; ++p) s += part[p * HBINS + bin];
    hist[bin] = s;
}

// ---------------- single-block select over 2048 bins ----------------
__global__ __launch_bounds__(1024) void select_stage(const unsigned* __restrict__ hist,
                                                     int* __restrict__ sel, int stage,
                                                     float* __restrict__ thr) {
    __shared__ unsigned sc[1024];
    __shared__ unsigned runs;
    int tid = threadIdx.x;
    unsigned Kr = (stage == 0) ? KRANK : (unsigned)sel[2 * stage - 1];
    if (tid == 0) runs = 0;
    __syncthreads();
    for (int ch = 0; ch < 2; ++ch) {
        unsigned v = hist[ch * 1024 + tid];
        sc[tid] = v;
        __syncthreads();
        for (int off = 1; off < 1024; off <<= 1) {
            unsigned t = (tid >= off) ? sc[tid - off] : 0u;
            __syncthreads();
            sc[tid] += t;
            __syncthreads();
        }
        unsigned incl = sc[tid];
        unsigned base = runs;
        unsigned lo = base + incl - v, hi = base + incl;
        if (Kr >= lo && Kr < hi) {
            int b = ch * 1024 + tid;
            sel[2 * stage] = b;
            sel[2 * stage + 1] = (int)(Kr - lo);
            if (stage == 2) {
                unsigned bits = ((unsigned)sel[0] << 21) | ((unsigned)sel[2] << 10) | (unsigned)b;
                thr[0] = __uint_as_float(bits);
            }
        }
        __syncthreads();
        if (tid == 1023) runs = base + incl;
        __syncthreads();
    }
}

// ---------------- prefix scan (3 kernels) ----------------
__global__ __launch_bounds__(1024) void scan1(const int* __restrict__ cnt,
                                              int* __restrict__ row_ptr,
                                              int* __restrict__ bsum,
                                              float* __restrict__ dis) {
    __shared__ int sc[1024];
    int tid = threadIdx.x;
    int i = blockIdx.x * 1024 + tid;
    int v = (i < NN) ? cnt[i] : 0;
    sc[tid] = v;
    __syncthreads();
    for (int off = 1; off < 1024; off <<= 1) {
        int t = (tid >= off) ? sc[tid - off] : 0;
        __syncthreads();
        sc[tid] += t;
        __syncthreads();
    }
    int incl = sc[tid];
    if (i < NN) {
        row_ptr[i + 1] = incl;                    // pre-offset inclusive scan
        dis[i] = rsqrtf((float)v + 1.0f);         // deg_inv_sqrt (with self loop)
    }
    if (tid == 1023) bsum[blockIdx.x] = incl;
}

__global__ __launch_bounds__(128) void scan2(const int* __restrict__ bsum,
                                             int* __restrict__ boff) {
    __shared__ int sc[128];
    int tid = threadIdx.x;
    int v = (tid < NB1) ? bsum[tid] : 0;
    sc[tid] = v;
    __syncthreads();
    for (int off = 1; off < 128; off <<= 1) {
        int t = (tid >= off) ? sc[tid - off] : 0;
        __syncthreads();
        sc[tid] += t;
        __syncthreads();
    }
    if (tid < NB1) boff[tid] = sc[tid] - v;       // exclusive block offsets
}

__global__ __launch_bounds__(1024) void scan3(const int* __restrict__ cnt,
                                              const int* __restrict__ boff,
                                              int* __restrict__ row_ptr,
                                              int* __restrict__ fill) {
    int i = blockIdx.x * 1024 + threadIdx.x;
    if (i >= NN) return;
    int incl = row_ptr[i + 1] + boff[blockIdx.x];
    row_ptr[i + 1] = incl;
    fill[i] = incl - cnt[i];                      // row start
    if (i == 0) row_ptr[0] = 0;
}

// ---------------- CSR fill ----------------
__global__ __launch_bounds__(256) void csr_fill(const int* __restrict__ srcv,
                                                const int* __restrict__ dstv,
                                                int* __restrict__ fill,
                                                int* __restrict__ csr_src) {
    int e = blockIdx.x * 256 + threadIdx.x;
    if (e >= NE) return;
    int p = atomicAdd(&fill[dstv[e]], 1);
    csr_src[p] = srcv[e];
}

// ---------------- GEMM1: h = x @ w1  (100000x512 @ 512x64), fp32 ----------------
__global__ __launch_bounds__(256) void gemm1(const float* __restrict__ x,
                                             const float* __restrict__ w1,
                                             float* __restrict__ h) {
    __shared__ float xs[32 * 72];   // [kk][r], pad 72 keeps 16B align + bank-free frag reads
    __shared__ float wsb[32 * 64];  // [kk][c]
    int tid = threadIdx.x;
    int rowBase = blockIdx.x * 64;
    int tr = tid & 15, tc = tid >> 4;
    float acc[4][4] = {};
    for (int k0 = 0; k0 < FIN; k0 += 32) {
#pragma unroll
        for (int i = 0; i < 8; ++i) {
            int lin = tid + 256 * i;
            int r = lin >> 5, kk = lin & 31;
            int gr = rowBase + r;
            float v = (gr < NN) ? x[gr * FIN + k0 + kk] : 0.f;
            xs[kk * 72 + r] = v;
        }
#pragma unroll
        for (int i = 0; i < 8; ++i) {
            int lin = tid + 256 * i;
            int kk = lin >> 6, c = lin & 63;
            wsb[kk * 64 + c] = w1[(k0 + kk) * FH + c];
        }
        __syncthreads();
#pragma unroll
        for (int kk = 0; kk < 32; ++kk) {
            float4 xv = *(const float4*)&xs[kk * 72 + tr * 4];
            float4 wv = *(const float4*)&wsb[kk * 64 + tc * 4];
            float xa[4] = {xv.x, xv.y, xv.z, xv.w};
            float wa[4] = {wv.x, wv.y, wv.z, wv.w};
#pragma unroll
            for (int a = 0; a < 4; ++a)
#pragma unroll
                for (int b = 0; b < 4; ++b) acc[a][b] = fmaf(xa[a], wa[b], acc[a][b]);
        }
        __syncthreads();
    }
#pragma unroll
    for (int a = 0; a < 4; ++a) {
        int gr = rowBase + tr * 4 + a;
        if (gr < NN) {
            float4 o = make_float4(acc[a][0], acc[a][1], acc[a][2], acc[a][3]);
            *(float4*)&h[gr * FH + tc * 4] = o;
        }
    }
}

// ---------------- aggregate layer 1 (+bias+relu), wave per node ----------------
__global__ __launch_bounds__(256) void agg_relu1(const float* __restrict__ h,
                                                 const float* __restrict__ dis,
                                                 const int* __restrict__ row_ptr,
                                                 const int* __restrict__ csr_src,
                                                 const float* __restrict__ b1,
                                                 float* __restrict__ h1) {
    int wave = threadIdx.x >> 6, lane = threadIdx.x & 63;
    int n = blockIdx.x * 4 + wave;
    if (n >= NN) return;
    float dn = dis[n];
    float acc = h[n * FH + lane] * (dn * dn);
    int e0 = row_ptr[n], e1 = row_ptr[n + 1];
    for (int e = e0; e < e1; ++e) {
        int s = csr_src[e];
        acc += h[s * FH + lane] * (dis[s] * dn);
    }
    float v = acc + b1[lane];
    h1[n * FH + lane] = fmaxf(v, 0.f);
}

// ---------------- GEMM2: h2 = h1 @ w2  (100000x64 @ 64x40) ----------------
// NOTE: all 64 lanes must stay ACTIVE through every __shfl — ds_bpermute from
// an EXEC-masked lane is undefined on CDNA.
__global__ __launch_bounds__(256) void gemm2(const float* __restrict__ h1,
                                             const float* __restrict__ w2,
                                             float* __restrict__ h2) {
    __shared__ float w2s[FH * FC];
    int tid = threadIdx.x;
    for (int i = tid; i < FH * FC; i += 256) w2s[i] = w2[i];
    __syncthreads();
    int wave = tid >> 6, lane = tid & 63;
    int n = blockIdx.x * 4 + wave;
    if (n >= NN) return;
    float hv = h1[n * FH + lane];   // all 64 lanes valid
    int cl = (lane < FC) ? lane : 0;
    float acc = 0.f;
#pragma unroll
    for (int k = 0; k < FH; ++k) {
        float xk = __shfl(hv, k);            // fully-active wave
        acc = fmaf(xk, w2s[k * FC + cl], acc);
    }
    if (lane < FC) h2[n * FC + lane] = acc;
}

// ---------------- aggregate layer 2 + bias + x2 + rnorm + log_softmax ----------------
__global__ __launch_bounds__(256) void agg2_fused(const float* __restrict__ h2,
                                                  const float* __restrict__ dis,
                                                  const int* __restrict__ row_ptr,
                                                  const int* __restrict__ csr_src,
                                                  const float* __restrict__ b2,
                                                  float* __restrict__ x2,
                                                  float* __restrict__ rnorm,
                                                  float* __restrict__ outls) {
    int wave = threadIdx.x >> 6, lane = threadIdx.x & 63;
    int n = blockIdx.x * 4 + wave;
    if (n >= NN) return;
    bool act = lane < FC;
    float dn = dis[n];
    float acc = act ? h2[n * FC + lane] * (dn * dn) : 0.f;
    int e0 = row_ptr[n], e1 = row_ptr[n + 1];
    for (int e = e0; e < e1; ++e) {
        int s = csr_src[e];
        float nw = dis[s] * dn;
        if (act) acc += h2[s * FC + lane] * nw;
    }
    float x2v = act ? acc + b2[lane] : -3.4e38f;
    if (act) x2[n * FC + lane] = x2v;
    float m = x2v;
#pragma unroll
    for (int off = 32; off; off >>= 1) m = fmaxf(m, __shfl_xor(m, off));
    float ex = act ? expf(x2v - m) : 0.f;
    float sq = act ? x2v * x2v : 0.f;
#pragma unroll
    for (int off = 32; off; off >>= 1) {
        ex += __shfl_xor(ex, off);
        sq += __shfl_xor(sq, off);
    }
    if (act) outls[n * FC + lane] = x2v - m - logf(ex);
    if (lane == 0) rnorm[n] = fmaxf(sqrtf(sq), 1e-8f);
}

// ---------------- edge loss ----------------
__global__ __launch_bounds__(256) void loss_kernel(const int* __restrict__ srcv,
                                                   const int* __restrict__ dstv,
                                                   const float* __restrict__ ew,
                                                   const float* __restrict__ lu,
                                                   const float* __restrict__ x2,
                                                   const float* __restrict__ rnorm,
                                                   const float* __restrict__ thr,
                                                   double* __restrict__ acc) {
    int e = blockIdx.x * 256 + threadIdx.x;
    float term = 0.f;
    if (e < NE) {
        int s = srcv[e], d = dstv[e];
        const float4* a = (const float4*)x2 + s * 10;
        const float4* b = (const float4*)x2 + d * 10;
        float dot = 0.f;
#pragma unroll
        for (int i = 0; i < 10; ++i) {
            float4 av = a[i], bv = b[i];
            dot += av.x * bv.x + av.y * bv.y + av.z * bv.z + av.w * bv.w;
        }
        float cosv = dot / (rnorm[s] * rnorm[d]);
        float cs = 1.f - cosv;
        float w = ew[e];
        bool mk = (w >= thr[0]);
        float lp = mk ? cs : 1.f - cs;
        float le = mk ? w : 1.f - w;
        term = le * lp * lu[e];
    }
#pragma unroll
    for (int off = 32; off; off >>= 1) term += __shfl_down(term, off);
    __shared__ float ws4[4];
    int lane = threadIdx.x & 63, wid = threadIdx.x >> 6;
    if (lane == 0) ws4[wid] = term;
    __syncthreads();
    if (threadIdx.x == 0) {
        double s = (double)ws4[0] + (double)ws4[1] + (double)ws4[2] + (double)ws4[3];
        atomicAdd(acc, s);
    }
}

__global__ void finalize(const double* __restrict__ acc, float* __restrict__ out) {
    out[NN * FC] = (float)(acc[0] * (1.0 / (double)NE));
}

// ---------------- host launch ----------------
extern "C" void kernel_launch(void* const* d_in, const int* in_sizes, int n_in,
                              void* d_out, int out_size, void* d_ws, size_t ws_size,
                              hipStream_t stream) {
    const float* x  = (const float*)d_in[0];
    const int*   ei = (const int*)d_in[1];
    const float* ew = (const float*)d_in[2];
    const float* lu = (const float*)d_in[3];
    const float* w1 = (const float*)d_in[4];
    const float* b1 = (const float*)d_in[5];
    const float* w2 = (const float*)d_in[6];
    const float* b2 = (const float*)d_in[7];
    float* out = (float*)d_out;
    const int* srcv = ei;
    const int* dstv = ei + NE;

    char* ws = (char*)d_ws;
    size_t off = 0;
    auto alloc = [&](size_t bytes) -> void* {
        void* p = ws + off;
        off += (bytes + 255) & ~(size_t)255;
        return p;
    };
    float*    dis     = (float*)alloc((size_t)NN * 4);
    int*      cnt     = (int*)alloc((size_t)NN * 4);
    int*      row_ptr = (int*)alloc((size_t)(NN + 1) * 4);
    int*      fill    = (int*)alloc((size_t)NN * 4);
    int*      csr_src = (int*)alloc((size_t)NE * 4);
    float*    h       = (float*)alloc((size_t)NN * FH * 4);
    float*    h1      = (float*)alloc((size_t)NN * FH * 4);
    float*    h2      = (float*)alloc((size_t)NN * FC * 4);
    float*    x2      = (float*)alloc((size_t)NN * FC * 4);
    float*    rnorm   = (float*)alloc((size_t)NN * 4);
    unsigned* part    = (unsigned*)alloc((size_t)HBLK * HBINS * 4);
    unsigned* histr   = (unsigned*)alloc((size_t)HBINS * 4);
    int*      bsum    = (int*)alloc(128 * 4);
    int*      boff    = (int*)alloc(128 * 4);
    int*      sel     = (int*)alloc(256);
    float*    thr     = (float*)alloc(256);
    double*   accd    = (double*)alloc(256);

    hipMemsetAsync(cnt, 0, (size_t)NN * 4, stream);
    hipMemsetAsync(accd, 0, 8, stream);

    const int EB = (NE + 255) / 256;      // 12500
    const int NB4 = (NN + 3) / 4;         // 25000

    deg_count<<<EB, 256, 0, stream>>>(dstv, cnt);
    // exact threshold: 3-stage radix select (11/11/10 bits), no global atomics
    hist_pass<<<HBLK, 256, 0, stream>>>(ew, sel, 0, part);
    hist_reduce<<<HBINS / 256, 256, 0, stream>>>(part, histr);
    select_stage<<<1, 1024, 0, stream>>>(histr, sel, 0, thr);
    hist_pass<<<HBLK, 256, 0, stream>>>(ew, sel, 1, part);
    hist_reduce<<<HBINS / 256, 256, 0, stream>>>(part, histr);
    select_stage<<<1, 1024, 0, stream>>>(histr, sel, 1, thr);
    hist_pass<<<HBLK, 256, 0, stream>>>(ew, sel, 2, part);
    hist_reduce<<<HBINS / 256, 256, 0, stream>>>(part, histr);
    select_stage<<<1, 1024, 0, stream>>>(histr, sel, 2, thr);

    scan1<<<NB1, 1024, 0, stream>>>(cnt, row_ptr, bsum, dis);
    scan2<<<1, 128, 0, stream>>>(bsum, boff);
    scan3<<<NB1, 1024, 0, stream>>>(cnt, boff, row_ptr, fill);
    csr_fill<<<EB, 256, 0, stream>>>(srcv, dstv, fill, csr_src);

    gemm1<<<(NN + 63) / 64, 256, 0, stream>>>(x, w1, h);
    agg_relu1<<<NB4, 256, 0, stream>>>(h, dis, row_ptr, csr_src, b1, h1);
    gemm2<<<NB4, 256, 0, stream>>>(h1, w2, h2);
    agg2_fused<<<NB4, 256, 0, stream>>>(h2, dis, row_ptr, csr_src, b2, x2, rnorm, out);
    loss_kernel<<<EB, 256, 0, stream>>>(srcv, dstv, ew, lu, x2, rnorm, thr, accd);
    finalize<<<1, 1, 0, stream>>>(accd, out);
}

// Round 4
// 1523.705 us; speedup vs baseline: 2.2902x; 1.2580x over previous
//
#include <hip/hip_runtime.h>

#define NN 100000
#define NE 3200000
#define FIN 512
#define FH 64
#define FC 40
#define KRANK 1600000u   // E - int(E*0.5), 0-indexed ascending rank
#define NB1 98           // ceil(NN/1024)
#define HBLK 128         // blocks for hist passes (NE/HBLK = 25000 exactly)
#define HBINS 2048

// ---- raw bf16 pack/unpack (round-to-nearest-even), no header-API risk ----
__device__ __forceinline__ unsigned f2b_rn(float x) {
    unsigned u = __float_as_uint(x);
    return (u + 0x7FFFu + ((u >> 16) & 1u)) >> 16;
}
__device__ __forceinline__ unsigned pack2(float x, float y) {
    return f2b_rn(x) | (f2b_rn(y) << 16);
}
__device__ __forceinline__ float2 unp2(unsigned u) {
    return make_float2(__uint_as_float(u << 16), __uint_as_float(u & 0xFFFF0000u));
}

// ---------------- degree count (spread atomics over 100k addresses) ----------------
__global__ __launch_bounds__(256) void deg_count(const int* __restrict__ dstv,
                                                 int* __restrict__ cnt) {
    int e = blockIdx.x * 256 + threadIdx.x;
    if (e >= NE) return;
    atomicAdd(&cnt[dstv[e]], 1);
}

// ---------------- LDS-privatized histogram pass (no global atomics) ----------------
__global__ __launch_bounds__(256) void hist_pass(const float* __restrict__ ew,
                                                 const int* __restrict__ sel,
                                                 int stage,
                                                 unsigned* __restrict__ part) {
    __shared__ unsigned lh[4 * HBINS];   // one sub-histogram per wave
    int tid = threadIdx.x, blk = blockIdx.x;
    int wv = tid >> 6;
    for (int i = tid; i < 4 * HBINS; i += 256) lh[i] = 0u;
    __syncthreads();
    unsigned m1 = 0, m2 = 0;
    if (stage == 1) m1 = (unsigned)sel[0];
    if (stage == 2) m2 = ((unsigned)sel[0] << 11) | (unsigned)sel[2];
    int base = blk * (NE / HBLK);
    for (int t = tid; t < NE / HBLK; t += 256) {
        unsigned bits = __float_as_uint(ew[base + t]);
        if (stage == 0) {
            atomicAdd(&lh[wv * HBINS + (bits >> 21)], 1u);
        } else if (stage == 1) {
            if ((bits >> 21) == m1) atomicAdd(&lh[wv * HBINS + ((bits >> 10) & 0x7FFu)], 1u);
        } else {
            if ((bits >> 10) == m2) atomicAdd(&lh[wv * HBINS + (bits & 0x3FFu)], 1u);
        }
    }
    __syncthreads();
    for (int i = tid; i < HBINS; i += 256)
        part[blk * HBINS + i] = lh[i] + lh[HBINS + i] + lh[2 * HBINS + i] + lh[3 * HBINS + i];
}

__global__ __launch_bounds__(256) void hist_reduce(const unsigned* __restrict__ part,
                                                   unsigned* __restrict__ hist) {
    int bin = blockIdx.x * 256 + threadIdx.x;   // grid 8 x 256 = 2048
    unsigned s = 0;
    for (int p = 0; p < HBLK; ++p) s += part[p * HBINS + bin];
    hist[bin] = s;
}

__global__ __launch_bounds__(1024) void select_stage(const unsigned* __restrict__ hist,
                                                     int* __restrict__ sel, int stage,
                                                     float* __restrict__ thr) {
    __shared__ unsigned sc[1024];
    __shared__ unsigned runs;
    int tid = threadIdx.x;
    unsigned Kr = (stage == 0) ? KRANK : (unsigned)sel[2 * stage - 1];
    if (tid == 0) runs = 0;
    __syncthreads();
    for (int ch = 0; ch < 2; ++ch) {
        unsigned v = hist[ch * 1024 + tid];
        sc[tid] = v;
        __syncthreads();
        for (int off = 1; off < 1024; off <<= 1) {
            unsigned t = (tid >= off) ? sc[tid - off] : 0u;
            __syncthreads();
            sc[tid] += t;
            __syncthreads();
        }
        unsigned incl = sc[tid];
        unsigned base = runs;
        unsigned lo = base + incl - v, hi = base + incl;
        if (Kr >= lo && Kr < hi) {
            int b = ch * 1024 + tid;
            sel[2 * stage] = b;
            sel[2 * stage + 1] = (int)(Kr - lo);
            if (stage == 2) {
                unsigned bits = ((unsigned)sel[0] << 21) | ((unsigned)sel[2] << 10) | (unsigned)b;
                thr[0] = __uint_as_float(bits);
            }
        }
        __syncthreads();
        if (tid == 1023) runs = base + incl;
        __syncthreads();
    }
}

// ---------------- prefix scan (3 kernels) ----------------
__global__ __launch_bounds__(1024) void scan1(const int* __restrict__ cnt,
                                              int* __restrict__ row_ptr,
                                              int* __restrict__ bsum,
                                              float* __restrict__ dis) {
    __shared__ int sc[1024];
    int tid = threadIdx.x;
    int i = blockIdx.x * 1024 + tid;
    int v = (i < NN) ? cnt[i] : 0;
    sc[tid] = v;
    __syncthreads();
    for (int off = 1; off < 1024; off <<= 1) {
        int t = (tid >= off) ? sc[tid - off] : 0;
        __syncthreads();
        sc[tid] += t;
        __syncthreads();
    }
    int incl = sc[tid];
    if (i < NN) {
        row_ptr[i + 1] = incl;
        dis[i] = rsqrtf((float)v + 1.0f);
    }
    if (tid == 1023) bsum[blockIdx.x] = incl;
}

__global__ __launch_bounds__(128) void scan2(const int* __restrict__ bsum,
                                             int* __restrict__ boff) {
    __shared__ int sc[128];
    int tid = threadIdx.x;
    int v = (tid < NB1) ? bsum[tid] : 0;
    sc[tid] = v;
    __syncthreads();
    for (int off = 1; off < 128; off <<= 1) {
        int t = (tid >= off) ? sc[tid - off] : 0;
        __syncthreads();
        sc[tid] += t;
        __syncthreads();
    }
    if (tid < NB1) boff[tid] = sc[tid] - v;
}

__global__ __launch_bounds__(1024) void scan3(const int* __restrict__ cnt,
                                              const int* __restrict__ boff,
                                              int* __restrict__ row_ptr,
                                              int* __restrict__ fill) {
    int i = blockIdx.x * 1024 + threadIdx.x;
    if (i >= NN) return;
    int incl = row_ptr[i + 1] + boff[blockIdx.x];
    row_ptr[i + 1] = incl;
    fill[i] = incl - cnt[i];
    if (i == 0) row_ptr[0] = 0;
}

// ---------------- CSR fill ----------------
__global__ __launch_bounds__(256) void csr_fill(const int* __restrict__ srcv,
                                                const int* __restrict__ dstv,
                                                int* __restrict__ fill,
                                                int* __restrict__ csr_src) {
    int e = blockIdx.x * 256 + threadIdx.x;
    if (e >= NE) return;
    int p = atomicAdd(&fill[dstv[e]], 1);
    csr_src[p] = srcv[e];
}

// ---------------- GEMM1: h = x @ w1, fp32 compute, bf16 store ----------------
__global__ __launch_bounds__(256) void gemm1(const float* __restrict__ x,
                                             const float* __restrict__ w1,
                                             unsigned short* __restrict__ hb) {
    __shared__ float xs[32 * 72];
    __shared__ float wsb[32 * 64];
    int tid = threadIdx.x;
    int rowBase = blockIdx.x * 64;
    int tr = tid & 15, tc = tid >> 4;
    float acc[4][4] = {};
    for (int k0 = 0; k0 < FIN; k0 += 32) {
#pragma unroll
        for (int i = 0; i < 8; ++i) {
            int lin = tid + 256 * i;
            int r = lin >> 5, kk = lin & 31;
            int gr = rowBase + r;
            float v = (gr < NN) ? x[gr * FIN + k0 + kk] : 0.f;
            xs[kk * 72 + r] = v;
        }
#pragma unroll
        for (int i = 0; i < 8; ++i) {
            int lin = tid + 256 * i;
            int kk = lin >> 6, c = lin & 63;
            wsb[kk * 64 + c] = w1[(k0 + kk) * FH + c];
        }
        __syncthreads();
#pragma unroll
        for (int kk = 0; kk < 32; ++kk) {
            float4 xv = *(const float4*)&xs[kk * 72 + tr * 4];
            float4 wv = *(const float4*)&wsb[kk * 64 + tc * 4];
            float xa[4] = {xv.x, xv.y, xv.z, xv.w};
            float wa[4] = {wv.x, wv.y, wv.z, wv.w};
#pragma unroll
            for (int a = 0; a < 4; ++a)
#pragma unroll
                for (int b = 0; b < 4; ++b) acc[a][b] = fmaf(xa[a], wa[b], acc[a][b]);
        }
        __syncthreads();
    }
#pragma unroll
    for (int a = 0; a < 4; ++a) {
        int gr = rowBase + tr * 4 + a;
        if (gr < NN) {
            uint2 u;
            u.x = pack2(acc[a][0], acc[a][1]);
            u.y = pack2(acc[a][2], acc[a][3]);
            *(uint2*)&hb[(size_t)gr * FH + tc * 4] = u;
        }
    }
}

// ---------------- aggregate layer 1 (+bias+relu), wave per node ----------------
// h stored bf16 (32 words/row). Lanes 0-31 = even CSR slots, 32-63 = odd slots;
// each lane holds features (2li, 2li+1). Halves combined via shfl_xor(32).
__global__ __launch_bounds__(256) void agg_relu1(const unsigned* __restrict__ hb,
                                                 const float* __restrict__ dis,
                                                 const int* __restrict__ row_ptr,
                                                 const int* __restrict__ csr_src,
                                                 const float* __restrict__ b1,
                                                 float* __restrict__ h1) {
    int wave = threadIdx.x >> 6, lane = threadIdx.x & 63;
    int n = blockIdx.x * 4 + wave;
    if (n >= NN) return;
    int half = lane >> 5, li = lane & 31;
    float dn = dis[n];
    float2 acc = make_float2(0.f, 0.f);
    if (half == 0) {
        float2 v = unp2(hb[(size_t)n * 32 + li]);
        float w = dn * dn;
        acc.x = v.x * w; acc.y = v.y * w;
    }
    int e0 = row_ptr[n], e1 = row_ptr[n + 1];
    int e = e0 + half;
    for (; e + 2 < e1; e += 4) {
        int s0 = csr_src[e], s1 = csr_src[e + 2];
        float w0 = dis[s0] * dn, w1w = dis[s1] * dn;
        float2 v0 = unp2(hb[(size_t)s0 * 32 + li]);
        float2 v1 = unp2(hb[(size_t)s1 * 32 + li]);
        acc.x = fmaf(v0.x, w0, acc.x); acc.y = fmaf(v0.y, w0, acc.y);
        acc.x = fmaf(v1.x, w1w, acc.x); acc.y = fmaf(v1.y, w1w, acc.y);
    }
    if (e < e1) {
        int s = csr_src[e];
        float w = dis[s] * dn;
        float2 v = unp2(hb[(size_t)s * 32 + li]);
        acc.x = fmaf(v.x, w, acc.x); acc.y = fmaf(v.y, w, acc.y);
    }
    // combine halves (full wave active)
    float ax = acc.x + __shfl_xor(acc.x, 32);
    float ay = acc.y + __shfl_xor(acc.y, 32);
    if (half == 0) {
        float2 b = ((const float2*)b1)[li];
        float2 o = make_float2(fmaxf(ax + b.x, 0.f), fmaxf(ay + b.y, 0.f));
        *(float2*)&h1[(size_t)n * FH + 2 * li] = o;
    }
}

// ---------------- GEMM2: h2 = h1 @ w2, bf16 store (20 words/row) ----------------
__global__ __launch_bounds__(256) void gemm2(const float* __restrict__ h1,
                                             const float* __restrict__ w2,
                                             unsigned* __restrict__ h2w) {
    __shared__ float w2s[FH * FC];
    int tid = threadIdx.x;
    for (int i = tid; i < FH * FC; i += 256) w2s[i] = w2[i];
    __syncthreads();
    int wave = tid >> 6, lane = tid & 63;
    int n = blockIdx.x * 4 + wave;
    if (n >= NN) return;
    float hv = h1[(size_t)n * FH + lane];
    int cl = (lane < FC) ? lane : 0;
    float acc = 0.f;
#pragma unroll
    for (int k = 0; k < FH; ++k) {
        float xk = __shfl(hv, k);            // fully-active wave
        acc = fmaf(xk, w2s[k * FC + cl], acc);
    }
    float lo = __shfl(acc, 2 * lane);
    float hi = __shfl(acc, 2 * lane + 1);
    if (lane < 20) h2w[(size_t)n * 20 + lane] = pack2(lo, hi);
}

// ---------------- aggregate layer 2 + bias + log_softmax + normalized bf16 x2 ----------------
__global__ __launch_bounds__(256) void agg2_fused(const unsigned* __restrict__ h2w,
                                                  const float* __restrict__ dis,
                                                  const int* __restrict__ row_ptr,
                                                  const int* __restrict__ csr_src,
                                                  const float* __restrict__ b2,
                                                  unsigned* __restrict__ x2nw,
                                                  float* __restrict__ outls) {
    int wave = threadIdx.x >> 6, lane = threadIdx.x & 63;
    int n = blockIdx.x * 4 + wave;
    if (n >= NN) return;
    int half = lane >> 5, li = lane & 31;
    bool ld = li < 20;
    int lidx = ld ? li : 19;
    float dn = dis[n];
    float2 acc = make_float2(0.f, 0.f);
    if (half == 0 && ld) {
        float2 v = unp2(h2w[(size_t)n * 20 + li]);
        float w = dn * dn;
        acc.x = v.x * w; acc.y = v.y * w;
    }
    int e0 = row_ptr[n], e1 = row_ptr[n + 1];
    int e = e0 + half;
    for (; e + 2 < e1; e += 4) {
        int s0 = csr_src[e], s1 = csr_src[e + 2];
        float w0 = dis[s0] * dn, w1w = dis[s1] * dn;
        float2 v0 = unp2(h2w[(size_t)s0 * 20 + lidx]);
        float2 v1 = unp2(h2w[(size_t)s1 * 20 + lidx]);
        if (ld) {
            acc.x = fmaf(v0.x, w0, acc.x); acc.y = fmaf(v0.y, w0, acc.y);
            acc.x = fmaf(v1.x, w1w, acc.x); acc.y = fmaf(v1.y, w1w, acc.y);
        }
    }
    if (e < e1) {
        int s = csr_src[e];
        float w = dis[s] * dn;
        float2 v = unp2(h2w[(size_t)s * 20 + lidx]);
        if (ld) { acc.x = fmaf(v.x, w, acc.x); acc.y = fmaf(v.y, w, acc.y); }
    }
    // combine halves (full wave active)
    float ax = acc.x + __shfl_xor(acc.x, 32);
    float ay = acc.y + __shfl_xor(acc.y, 32);
    bool actv = (half == 0) && ld;
    float2 x2v;
    if (actv) {
        float2 b = ((const float2*)b2)[li];
        x2v = make_float2(ax + b.x, ay + b.y);
    } else {
        x2v = make_float2(-3.4e38f, -3.4e38f);
    }
    float m = fmaxf(x2v.x, x2v.y);
#pragma unroll
    for (int off = 16; off; off >>= 1) m = fmaxf(m, __shfl_xor(m, off));
    float ex = actv ? (expf(x2v.x - m) + expf(x2v.y - m)) : 0.f;
    float sq = actv ? (x2v.x * x2v.x + x2v.y * x2v.y) : 0.f;
#pragma unroll
    for (int off = 16; off; off >>= 1) {
        ex += __shfl_xor(ex, off);
        sq += __shfl_xor(sq, off);
    }
    if (actv) {
        float lse = m + logf(ex);
        *(float2*)&outls[(size_t)n * FC + 2 * li] = make_float2(x2v.x - lse, x2v.y - lse);
        float inv = 1.f / fmaxf(sqrtf(sq), 1e-8f);
        x2nw[(size_t)n * 20 + li] = pack2(x2v.x * inv, x2v.y * inv);
    }
}

// ---------------- edge loss: cos = dot of pre-normalized bf16 rows ----------------
__global__ __launch_bounds__(256) void loss_kernel(const int* __restrict__ srcv,
                                                   const int* __restrict__ dstv,
                                                   const float* __restrict__ ew,
                                                   const float* __restrict__ lu,
                                                   const unsigned* __restrict__ x2nw,
                                                   const float* __restrict__ thr,
                                                   double* __restrict__ acc) {
    int e = blockIdx.x * 256 + threadIdx.x;
    float term = 0.f;
    if (e < NE) {
        int s = srcv[e], d = dstv[e];
        const uint4* pa = (const uint4*)(x2nw + (size_t)s * 20);
        const uint4* pb = (const uint4*)(x2nw + (size_t)d * 20);
        float dot = 0.f;
#pragma unroll
        for (int i = 0; i < 5; ++i) {
            uint4 av = pa[i], bv = pb[i];
            float2 a0 = unp2(av.x), b0 = unp2(bv.x);
            float2 a1 = unp2(av.y), b1v = unp2(bv.y);
            float2 a2 = unp2(av.z), b2v = unp2(bv.z);
            float2 a3 = unp2(av.w), b3 = unp2(bv.w);
            dot += a0.x * b0.x + a0.y * b0.y + a1.x * b1v.x + a1.y * b1v.y
                 + a2.x * b2v.x + a2.y * b2v.y + a3.x * b3.x + a3.y * b3.y;
        }
        float cs = 1.f - dot;
        float w = ew[e];
        bool mk = (w >= thr[0]);
        float lp = mk ? cs : 1.f - cs;
        float le = mk ? w : 1.f - w;
        term = le * lp * lu[e];
    }
#pragma unroll
    for (int off = 32; off; off >>= 1) term += __shfl_down(term, off);
    __shared__ float ws4[4];
    int lane = threadIdx.x & 63, wid = threadIdx.x >> 6;
    if (lane == 0) ws4[wid] = term;
    __syncthreads();
    if (threadIdx.x == 0) {
        double s = (double)ws4[0] + (double)ws4[1] + (double)ws4[2] + (double)ws4[3];
        atomicAdd(acc, s);
    }
}

__global__ void finalize(const double* __restrict__ acc, float* __restrict__ out) {
    out[NN * FC] = (float)(acc[0] * (1.0 / (double)NE));
}

// ---------------- host launch ----------------
extern "C" void kernel_launch(void* const* d_in, const int* in_sizes, int n_in,
                              void* d_out, int out_size, void* d_ws, size_t ws_size,
                              hipStream_t stream) {
    const float* x  = (const float*)d_in[0];
    const int*   ei = (const int*)d_in[1];
    const float* ew = (const float*)d_in[2];
    const float* lu = (const float*)d_in[3];
    const float* w1 = (const float*)d_in[4];
    const float* b1 = (const float*)d_in[5];
    const float* w2 = (const float*)d_in[6];
    const float* b2 = (const float*)d_in[7];
    float* out = (float*)d_out;
    const int* srcv = ei;
    const int* dstv = ei + NE;

    char* ws = (char*)d_ws;
    size_t off = 0;
    auto alloc = [&](size_t bytes) -> void* {
        void* p = ws + off;
        off += (bytes + 255) & ~(size_t)255;
        return p;
    };
    float*    dis     = (float*)alloc((size_t)NN * 4);
    int*      cnt     = (int*)alloc((size_t)NN * 4);
    int*      row_ptr = (int*)alloc((size_t)(NN + 1) * 4);
    int*      fill    = (int*)alloc((size_t)NN * 4);
    int*      csr_src = (int*)alloc((size_t)NE * 4);
    unsigned short* hb = (unsigned short*)alloc((size_t)NN * FH * 2);   // bf16 h
    float*    h1      = (float*)alloc((size_t)NN * FH * 4);
    unsigned* h2w     = (unsigned*)alloc((size_t)NN * 20 * 4);          // bf16x2 h2
    unsigned* x2nw    = (unsigned*)alloc((size_t)NN * 20 * 4);          // bf16x2 normalized x2
    unsigned* part    = (unsigned*)alloc((size_t)HBLK * HBINS * 4);
    unsigned* histr   = (unsigned*)alloc((size_t)HBINS * 4);
    int*      bsum    = (int*)alloc(128 * 4);
    int*      boff    = (int*)alloc(128 * 4);
    int*      sel     = (int*)alloc(256);
    float*    thr     = (float*)alloc(256);
    double*   accd    = (double*)alloc(256);

    hipMemsetAsync(cnt, 0, (size_t)NN * 4, stream);
    hipMemsetAsync(accd, 0, 8, stream);

    const int EB = (NE + 255) / 256;      // 12500
    const int NB4 = (NN + 3) / 4;         // 25000

    deg_count<<<EB, 256, 0, stream>>>(dstv, cnt);
    hist_pass<<<HBLK, 256, 0, stream>>>(ew, sel, 0, part);
    hist_reduce<<<HBINS / 256, 256, 0, stream>>>(part, histr);
    select_stage<<<1, 1024, 0, stream>>>(histr, sel, 0, thr);
    hist_pass<<<HBLK, 256, 0, stream>>>(ew, sel, 1, part);
    hist_reduce<<<HBINS / 256, 256, 0, stream>>>(part, histr);
    select_stage<<<1, 1024, 0, stream>>>(histr, sel, 1, thr);
    hist_pass<<<HBLK, 256, 0, stream>>>(ew, sel, 2, part);
    hist_reduce<<<HBINS / 256, 256, 0, stream>>>(part, histr);
    select_stage<<<1, 1024, 0, stream>>>(histr, sel, 2, thr);

    scan1<<<NB1, 1024, 0, stream>>>(cnt, row_ptr, bsum, dis);
    scan2<<<1, 128, 0, stream>>>(bsum, boff);
    scan3<<<NB1, 1024, 0, stream>>>(cnt, boff, row_ptr, fill);
    csr_fill<<<EB, 256, 0, stream>>>(srcv, dstv, fill, csr_src);

    gemm1<<<(NN + 63) / 64, 256, 0, stream>>>(x, w1, hb);
    agg_relu1<<<NB4, 256, 0, stream>>>((const unsigned*)hb, dis, row_ptr, csr_src, b1, h1);
    gemm2<<<NB4, 256, 0, stream>>>(h1, w2, h2w);
    agg2_fused<<<NB4, 256, 0, stream>>>(h2w, dis, row_ptr, csr_src, b2, x2nw, out);
    loss_kernel<<<EB, 256, 0, stream>>>(srcv, dstv, ew, lu, x2nw, thr, accd);
    finalize<<<1, 1, 0, stream>>>(accd, out);
}

// Round 5
// 1252.722 us; speedup vs baseline: 2.7856x; 1.2163x over previous
//
#include <hip/hip_runtime.h>

#define NN 100000
#define NE 3200000
#define FIN 512
#define FH 64
#define FC 40
#define KRANK 1600000u   // E - int(E*0.5), 0-indexed ascending rank
#define HBLK 128         // blocks for hist passes (NE/HBLK = 25000 exactly)
#define HBINS 2048
#define NBUCK 391        // ceil(NN/256) buckets of 256 dst-nodes
#define BPAD 512
#define SBLK 250         // scatter blocks; NE/SBLK = 12800 exactly
#define EPB 12800

// ---- raw bf16 pack/unpack (round-to-nearest-even) ----
__device__ __forceinline__ unsigned f2b_rn(float x) {
    unsigned u = __float_as_uint(x);
    return (u + 0x7FFFu + ((u >> 16) & 1u)) >> 16;
}
__device__ __forceinline__ unsigned pack2(float x, float y) {
    return f2b_rn(x) | (f2b_rn(y) << 16);
}
__device__ __forceinline__ float2 unp2(unsigned u) {
    return make_float2(__uint_as_float(u << 16), __uint_as_float(u & 0xFFFF0000u));
}

// ================= bucketed CSR construction =================
// bucket b = dst >> 8. All scattered writes confined to ~32KB bucket windows.

__global__ __launch_bounds__(256) void bucket_count(const int* __restrict__ dstv,
                                                    unsigned* __restrict__ bcnt) {
    __shared__ unsigned bh[4 * BPAD];
    int tid = threadIdx.x, wv = tid >> 6;
    for (int i = tid; i < 4 * BPAD; i += 256) bh[i] = 0u;
    __syncthreads();
    int base = blockIdx.x * EPB;
    for (int t = tid; t < EPB; t += 256) {
        int b = dstv[base + t] >> 8;
        atomicAdd(&bh[wv * BPAD + b], 1u);
    }
    __syncthreads();
    for (int i = tid; i < BPAD; i += 256) {
        unsigned s = bh[i] + bh[BPAD + i] + bh[2 * BPAD + i] + bh[3 * BPAD + i];
        if (s) atomicAdd(&bcnt[i], s);
    }
}

__global__ __launch_bounds__(512) void bucket_scan(const unsigned* __restrict__ bcnt,
                                                   unsigned* __restrict__ boff,
                                                   unsigned* __restrict__ bfill,
                                                   int* __restrict__ row_ptr) {
    __shared__ unsigned sc[512];
    int tid = threadIdx.x;
    unsigned v = (tid < NBUCK) ? bcnt[tid] : 0u;
    sc[tid] = v;
    __syncthreads();
    for (int off = 1; off < 512; off <<= 1) {
        unsigned t = (tid >= off) ? sc[tid - off] : 0u;
        __syncthreads();
        sc[tid] += t;
        __syncthreads();
    }
    unsigned excl = sc[tid] - v;        // boff[NBUCK] lands at NE naturally
    boff[tid] = excl;
    bfill[tid] = excl;
    if (tid == 0) row_ptr[NN] = NE;
}

__global__ __launch_bounds__(256) void bucket_scatter(const int* __restrict__ srcv,
                                                      const int* __restrict__ dstv,
                                                      unsigned* __restrict__ bfill,
                                                      unsigned* __restrict__ bp) {
    __shared__ unsigned bh[4 * BPAD];
    __shared__ unsigned bbase[BPAD];
    __shared__ unsigned bfl[BPAD];
    int tid = threadIdx.x, wv = tid >> 6;
    for (int i = tid; i < 4 * BPAD; i += 256) bh[i] = 0u;
    __syncthreads();
    int base = blockIdx.x * EPB;
    for (int t = tid; t < EPB; t += 256) {
        int b = dstv[base + t] >> 8;
        atomicAdd(&bh[wv * BPAD + b], 1u);
    }
    __syncthreads();
    for (int i = tid; i < BPAD; i += 256) {
        unsigned s = bh[i] + bh[BPAD + i] + bh[2 * BPAD + i] + bh[3 * BPAD + i];
        bbase[i] = s ? atomicAdd(&bfill[i], s) : 0u;   // one reservation per (block,bucket)
        bfl[i] = 0u;
    }
    __syncthreads();
    for (int t = tid; t < EPB; t += 256) {
        int d = dstv[base + t];
        int b = d >> 8;
        unsigned r = atomicAdd(&bfl[b], 1u);
        unsigned pk = (unsigned)srcv[base + t] | ((unsigned)(d & 255) << 17);  // src<2^17
        bp[bbase[b] + r] = pk;
    }
}

// one block per bucket: exact degrees -> dis + row_ptr, then in-bucket CSR place
__global__ __launch_bounds__(256) void bucket_build(const unsigned* __restrict__ bp,
                                                    const unsigned* __restrict__ boff,
                                                    int* __restrict__ row_ptr,
                                                    float* __restrict__ dis,
                                                    int* __restrict__ csr_src) {
    __shared__ unsigned lh[4 * 256];
    __shared__ unsigned sc[256];
    __shared__ unsigned gbase[256];
    __shared__ unsigned fl2[256];
    int b = blockIdx.x, tid = threadIdx.x, wv = tid >> 6;
    unsigned e0 = boff[b], e1 = boff[b + 1];
    int ecnt = (int)(e1 - e0);
    for (int i = tid; i < 1024; i += 256) lh[i] = 0u;
    __syncthreads();
    for (int t = tid; t < ecnt; t += 256) {
        unsigned lid = bp[e0 + t] >> 17;
        atomicAdd(&lh[wv * 256 + lid], 1u);
    }
    __syncthreads();
    unsigned deg = lh[tid] + lh[256 + tid] + lh[512 + tid] + lh[768 + tid];
    sc[tid] = deg;
    __syncthreads();
    for (int off = 1; off < 256; off <<= 1) {
        unsigned t = (tid >= off) ? sc[tid - off] : 0u;
        __syncthreads();
        sc[tid] += t;
        __syncthreads();
    }
    unsigned excl = sc[tid] - deg;
    gbase[tid] = e0 + excl;
    fl2[tid] = 0u;
    int n = b * 256 + tid;
    if (n < NN) {
        row_ptr[n] = (int)(e0 + excl);
        dis[n] = rsqrtf((float)deg + 1.0f);
    }
    __syncthreads();
    for (int t = tid; t < ecnt; t += 256) {
        unsigned v = bp[e0 + t];
        unsigned lid = v >> 17;
        unsigned r = atomicAdd(&fl2[lid], 1u);
        csr_src[gbase[lid] + r] = (int)(v & 0x1FFFFu);
    }
}

// ================= threshold: 3-stage radix select =================
__global__ __launch_bounds__(256) void hist_pass(const float* __restrict__ ew,
                                                 const int* __restrict__ sel,
                                                 int stage,
                                                 unsigned* __restrict__ part) {
    __shared__ unsigned lh[4 * HBINS];
    int tid = threadIdx.x, blk = blockIdx.x;
    int wv = tid >> 6;
    for (int i = tid; i < 4 * HBINS; i += 256) lh[i] = 0u;
    __syncthreads();
    unsigned m1 = 0, m2 = 0;
    if (stage == 1) m1 = (unsigned)sel[0];
    if (stage == 2) m2 = ((unsigned)sel[0] << 11) | (unsigned)sel[2];
    int base = blk * (NE / HBLK);
    for (int t = tid; t < NE / HBLK; t += 256) {
        unsigned bits = __float_as_uint(ew[base + t]);
        if (stage == 0) {
            atomicAdd(&lh[wv * HBINS + (bits >> 21)], 1u);
        } else if (stage == 1) {
            if ((bits >> 21) == m1) atomicAdd(&lh[wv * HBINS + ((bits >> 10) & 0x7FFu)], 1u);
        } else {
            if ((bits >> 10) == m2) atomicAdd(&lh[wv * HBINS + (bits & 0x3FFu)], 1u);
        }
    }
    __syncthreads();
    for (int i = tid; i < HBINS; i += 256)
        part[blk * HBINS + i] = lh[i] + lh[HBINS + i] + lh[2 * HBINS + i] + lh[3 * HBINS + i];
}

__global__ __launch_bounds__(256) void hist_reduce(const unsigned* __restrict__ part,
                                                   unsigned* __restrict__ hist) {
    int bin = blockIdx.x * 256 + threadIdx.x;
    unsigned s = 0;
    for (int p = 0; p < HBLK; ++p) s += part[p * HBINS + bin];
    hist[bin] = s;
}

__global__ __launch_bounds__(1024) void select_stage(const unsigned* __restrict__ hist,
                                                     int* __restrict__ sel, int stage,
                                                     float* __restrict__ thr) {
    __shared__ unsigned sc[1024];
    __shared__ unsigned runs;
    int tid = threadIdx.x;
    unsigned Kr = (stage == 0) ? KRANK : (unsigned)sel[2 * stage - 1];
    if (tid == 0) runs = 0;
    __syncthreads();
    for (int ch = 0; ch < 2; ++ch) {
        unsigned v = hist[ch * 1024 + tid];
        sc[tid] = v;
        __syncthreads();
        for (int off = 1; off < 1024; off <<= 1) {
            unsigned t = (tid >= off) ? sc[tid - off] : 0u;
            __syncthreads();
            sc[tid] += t;
            __syncthreads();
        }
        unsigned incl = sc[tid];
        unsigned base = runs;
        unsigned lo = base + incl - v, hi = base + incl;
        if (Kr >= lo && Kr < hi) {
            int b = ch * 1024 + tid;
            sel[2 * stage] = b;
            sel[2 * stage + 1] = (int)(Kr - lo);
            if (stage == 2) {
                unsigned bits = ((unsigned)sel[0] << 21) | ((unsigned)sel[2] << 10) | (unsigned)b;
                thr[0] = __uint_as_float(bits);
            }
        }
        __syncthreads();
        if (tid == 1023) runs = base + incl;
        __syncthreads();
    }
}

// ================= GEMM1: h = x @ w1, fp32 compute, bf16 store =================
__global__ __launch_bounds__(256) void gemm1(const float* __restrict__ x,
                                             const float* __restrict__ w1,
                                             unsigned short* __restrict__ hb) {
    __shared__ float xs[32 * 72];
    __shared__ float wsb[32 * 64];
    int tid = threadIdx.x;
    int rowBase = blockIdx.x * 64;
    int tr = tid & 15, tc = tid >> 4;
    float acc[4][4] = {};
    for (int k0 = 0; k0 < FIN; k0 += 32) {
#pragma unroll
        for (int i = 0; i < 8; ++i) {
            int lin = tid + 256 * i;
            int r = lin >> 5, kk = lin & 31;
            int gr = rowBase + r;
            float v = (gr < NN) ? x[gr * FIN + k0 + kk] : 0.f;
            xs[kk * 72 + r] = v;
        }
#pragma unroll
        for (int i = 0; i < 8; ++i) {
            int lin = tid + 256 * i;
            int kk = lin >> 6, c = lin & 63;
            wsb[kk * 64 + c] = w1[(k0 + kk) * FH + c];
        }
        __syncthreads();
#pragma unroll
        for (int kk = 0; kk < 32; ++kk) {
            float4 xv = *(const float4*)&xs[kk * 72 + tr * 4];
            float4 wv = *(const float4*)&wsb[kk * 64 + tc * 4];
            float xa[4] = {xv.x, xv.y, xv.z, xv.w};
            float wa[4] = {wv.x, wv.y, wv.z, wv.w};
#pragma unroll
            for (int a = 0; a < 4; ++a)
#pragma unroll
                for (int b = 0; b < 4; ++b) acc[a][b] = fmaf(xa[a], wa[b], acc[a][b]);
        }
        __syncthreads();
    }
#pragma unroll
    for (int a = 0; a < 4; ++a) {
        int gr = rowBase + tr * 4 + a;
        if (gr < NN) {
            uint2 u;
            u.x = pack2(acc[a][0], acc[a][1]);
            u.y = pack2(acc[a][2], acc[a][3]);
            *(uint2*)&hb[(size_t)gr * FH + tc * 4] = u;
        }
    }
}

// ================= aggregate layer 1 (+bias+relu), wave per node =================
__global__ __launch_bounds__(256) void agg_relu1(const unsigned* __restrict__ hb,
                                                 const float* __restrict__ dis,
                                                 const int* __restrict__ row_ptr,
                                                 const int* __restrict__ csr_src,
                                                 const float* __restrict__ b1,
                                                 float* __restrict__ h1) {
    int wave = threadIdx.x >> 6, lane = threadIdx.x & 63;
    int n = blockIdx.x * 4 + wave;
    if (n >= NN) return;
    int half = lane >> 5, li = lane & 31;
    float dn = dis[n];
    float2 acc = make_float2(0.f, 0.f);
    if (half == 0) {
        float2 v = unp2(hb[(size_t)n * 32 + li]);
        float w = dn * dn;
        acc.x = v.x * w; acc.y = v.y * w;
    }
    int e0 = row_ptr[n], e1 = row_ptr[n + 1];
    int e = e0 + half;
    for (; e + 2 < e1; e += 4) {
        int s0 = csr_src[e], s1 = csr_src[e + 2];
        float w0 = dis[s0] * dn, w1w = dis[s1] * dn;
        float2 v0 = unp2(hb[(size_t)s0 * 32 + li]);
        float2 v1 = unp2(hb[(size_t)s1 * 32 + li]);
        acc.x = fmaf(v0.x, w0, acc.x); acc.y = fmaf(v0.y, w0, acc.y);
        acc.x = fmaf(v1.x, w1w, acc.x); acc.y = fmaf(v1.y, w1w, acc.y);
    }
    if (e < e1) {
        int s = csr_src[e];
        float w = dis[s] * dn;
        float2 v = unp2(hb[(size_t)s * 32 + li]);
        acc.x = fmaf(v.x, w, acc.x); acc.y = fmaf(v.y, w, acc.y);
    }
    float ax = acc.x + __shfl_xor(acc.x, 32);
    float ay = acc.y + __shfl_xor(acc.y, 32);
    if (half == 0) {
        float2 b = ((const float2*)b1)[li];
        float2 o = make_float2(fmaxf(ax + b.x, 0.f), fmaxf(ay + b.y, 0.f));
        *(float2*)&h1[(size_t)n * FH + 2 * li] = o;
    }
}

// ================= GEMM2: h2 = h1 @ w2, bf16 store (20 words/row) =================
__global__ __launch_bounds__(256) void gemm2(const float* __restrict__ h1,
                                             const float* __restrict__ w2,
                                             unsigned* __restrict__ h2w) {
    __shared__ float w2s[FH * FC];
    int tid = threadIdx.x;
    for (int i = tid; i < FH * FC; i += 256) w2s[i] = w2[i];
    __syncthreads();
    int wave = tid >> 6, lane = tid & 63;
    int n = blockIdx.x * 4 + wave;
    if (n >= NN) return;
    float hv = h1[(size_t)n * FH + lane];
    int cl = (lane < FC) ? lane : 0;
    float acc = 0.f;
#pragma unroll
    for (int k = 0; k < FH; ++k) {
        float xk = __shfl(hv, k);
        acc = fmaf(xk, w2s[k * FC + cl], acc);
    }
    float lo = __shfl(acc, 2 * lane);
    float hi = __shfl(acc, 2 * lane + 1);
    if (lane < 20) h2w[(size_t)n * 20 + lane] = pack2(lo, hi);
}

// ============ aggregate layer 2 + bias + log_softmax + normalized bf16 x2 ============
__global__ __launch_bounds__(256) void agg2_fused(const unsigned* __restrict__ h2w,
                                                  const float* __restrict__ dis,
                                                  const int* __restrict__ row_ptr,
                                                  const int* __restrict__ csr_src,
                                                  const float* __restrict__ b2,
                                                  unsigned* __restrict__ x2nw,
                                                  float* __restrict__ outls) {
    int wave = threadIdx.x >> 6, lane = threadIdx.x & 63;
    int n = blockIdx.x * 4 + wave;
    if (n >= NN) return;
    int half = lane >> 5, li = lane & 31;
    bool ld = li < 20;
    int lidx = ld ? li : 19;
    float dn = dis[n];
    float2 acc = make_float2(0.f, 0.f);
    if (half == 0 && ld) {
        float2 v = unp2(h2w[(size_t)n * 20 + li]);
        float w = dn * dn;
        acc.x = v.x * w; acc.y = v.y * w;
    }
    int e0 = row_ptr[n], e1 = row_ptr[n + 1];
    int e = e0 + half;
    for (; e + 2 < e1; e += 4) {
        int s0 = csr_src[e], s1 = csr_src[e + 2];
        float w0 = dis[s0] * dn, w1w = dis[s1] * dn;
        float2 v0 = unp2(h2w[(size_t)s0 * 20 + lidx]);
        float2 v1 = unp2(h2w[(size_t)s1 * 20 + lidx]);
        if (ld) {
            acc.x = fmaf(v0.x, w0, acc.x); acc.y = fmaf(v0.y, w0, acc.y);
            acc.x = fmaf(v1.x, w1w, acc.x); acc.y = fmaf(v1.y, w1w, acc.y);
        }
    }
    if (e < e1) {
        int s = csr_src[e];
        float w = dis[s] * dn;
        float2 v = unp2(h2w[(size_t)s * 20 + lidx]);
        if (ld) { acc.x = fmaf(v.x, w, acc.x); acc.y = fmaf(v.y, w, acc.y); }
    }
    float ax = acc.x + __shfl_xor(acc.x, 32);
    float ay = acc.y + __shfl_xor(acc.y, 32);
    bool actv = (half == 0) && ld;
    float2 x2v;
    if (actv) {
        float2 b = ((const float2*)b2)[li];
        x2v = make_float2(ax + b.x, ay + b.y);
    } else {
        x2v = make_float2(-3.4e38f, -3.4e38f);
    }
    float m = fmaxf(x2v.x, x2v.y);
#pragma unroll
    for (int off = 16; off; off >>= 1) m = fmaxf(m, __shfl_xor(m, off));
    float ex = actv ? (expf(x2v.x - m) + expf(x2v.y - m)) : 0.f;
    float sq = actv ? (x2v.x * x2v.x + x2v.y * x2v.y) : 0.f;
#pragma unroll
    for (int off = 16; off; off >>= 1) {
        ex += __shfl_xor(ex, off);
        sq += __shfl_xor(sq, off);
    }
    if (actv) {
        float lse = m + logf(ex);
        *(float2*)&outls[(size_t)n * FC + 2 * li] = make_float2(x2v.x - lse, x2v.y - lse);
        float inv = 1.f / fmaxf(sqrtf(sq), 1e-8f);
        x2nw[(size_t)n * 20 + li] = pack2(x2v.x * inv, x2v.y * inv);
    }
}

// ================= edge loss: cos = dot of pre-normalized bf16 rows =================
__global__ __launch_bounds__(256) void loss_kernel(const int* __restrict__ srcv,
                                                   const int* __restrict__ dstv,
                                                   const float* __restrict__ ew,
                                                   const float* __restrict__ lu,
                                                   const unsigned* __restrict__ x2nw,
                                                   const float* __restrict__ thr,
                                                   double* __restrict__ acc) {
    int e = blockIdx.x * 256 + threadIdx.x;
    float term = 0.f;
    if (e < NE) {
        int s = srcv[e], d = dstv[e];
        const uint4* pa = (const uint4*)(x2nw + (size_t)s * 20);
        const uint4* pb = (const uint4*)(x2nw + (size_t)d * 20);
        float dot = 0.f;
#pragma unroll
        for (int i = 0; i < 5; ++i) {
            uint4 av = pa[i], bv = pb[i];
            float2 a0 = unp2(av.x), b0 = unp2(bv.x);
            float2 a1 = unp2(av.y), b1v = unp2(bv.y);
            float2 a2 = unp2(av.z), b2v = unp2(bv.z);
            float2 a3 = unp2(av.w), b3 = unp2(bv.w);
            dot += a0.x * b0.x + a0.y * b0.y + a1.x * b1v.x + a1.y * b1v.y
                 + a2.x * b2v.x + a2.y * b2v.y + a3.x * b3.x + a3.y * b3.y;
        }
        float cs = 1.f - dot;
        float w = ew[e];
        bool mk = (w >= thr[0]);
        float lp = mk ? cs : 1.f - cs;
        float le = mk ? w : 1.f - w;
        term = le * lp * lu[e];
    }
#pragma unroll
    for (int off = 32; off; off >>= 1) term += __shfl_down(term, off);
    __shared__ float ws4[4];
    int lane = threadIdx.x & 63, wid = threadIdx.x >> 6;
    if (lane == 0) ws4[wid] = term;
    __syncthreads();
    if (threadIdx.x == 0) {
        double s = (double)ws4[0] + (double)ws4[1] + (double)ws4[2] + (double)ws4[3];
        atomicAdd(acc, s);
    }
}

__global__ void finalize(const double* __restrict__ acc, float* __restrict__ out) {
    out[NN * FC] = (float)(acc[0] * (1.0 / (double)NE));
}

// ================= host launch =================
extern "C" void kernel_launch(void* const* d_in, const int* in_sizes, int n_in,
                              void* d_out, int out_size, void* d_ws, size_t ws_size,
                              hipStream_t stream) {
    const float* x  = (const float*)d_in[0];
    const int*   ei = (const int*)d_in[1];
    const float* ew = (const float*)d_in[2];
    const float* lu = (const float*)d_in[3];
    const float* w1 = (const float*)d_in[4];
    const float* b1 = (const float*)d_in[5];
    const float* w2 = (const float*)d_in[6];
    const float* b2 = (const float*)d_in[7];
    float* out = (float*)d_out;
    const int* srcv = ei;
    const int* dstv = ei + NE;

    char* ws = (char*)d_ws;
    size_t off = 0;
    auto alloc = [&](size_t bytes) -> void* {
        void* p = ws + off;
        off += (bytes + 255) & ~(size_t)255;
        return p;
    };
    float*    dis     = (float*)alloc((size_t)NN * 4);
    int*      row_ptr = (int*)alloc((size_t)(NN + 1) * 4);
    int*      csr_src = (int*)alloc((size_t)NE * 4);
    unsigned* bp      = (unsigned*)alloc((size_t)NE * 4);     // packed (src | lid<<17)
    unsigned* bcnt    = (unsigned*)alloc((size_t)BPAD * 4);
    unsigned* boff2   = (unsigned*)alloc((size_t)BPAD * 4);
    unsigned* bfill   = (unsigned*)alloc((size_t)BPAD * 4);
    unsigned short* hb = (unsigned short*)alloc((size_t)NN * FH * 2);
    float*    h1      = (float*)alloc((size_t)NN * FH * 4);
    unsigned* h2w     = (unsigned*)alloc((size_t)NN * 20 * 4);
    unsigned* x2nw    = (unsigned*)alloc((size_t)NN * 20 * 4);
    unsigned* part    = (unsigned*)alloc((size_t)HBLK * HBINS * 4);
    unsigned* histr   = (unsigned*)alloc((size_t)HBINS * 4);
    int*      sel     = (int*)alloc(256);
    float*    thr     = (float*)alloc(256);
    double*   accd    = (double*)alloc(256);

    hipMemsetAsync(bcnt, 0, (size_t)BPAD * 4, stream);
    hipMemsetAsync(accd, 0, 8, stream);

    const int EB = (NE + 255) / 256;      // 12500
    const int NB4 = (NN + 3) / 4;         // 25000

    // bucketed CSR (replaces deg_count + 100k scan + csr_fill)
    bucket_count<<<SBLK, 256, 0, stream>>>(dstv, bcnt);
    bucket_scan<<<1, 512, 0, stream>>>(bcnt, boff2, bfill, row_ptr);
    bucket_scatter<<<SBLK, 256, 0, stream>>>(srcv, dstv, bfill, bp);
    bucket_build<<<NBUCK, 256, 0, stream>>>(bp, boff2, row_ptr, dis, csr_src);

    // exact threshold: 3-stage radix select
    hist_pass<<<HBLK, 256, 0, stream>>>(ew, sel, 0, part);
    hist_reduce<<<HBINS / 256, 256, 0, stream>>>(part, histr);
    select_stage<<<1, 1024, 0, stream>>>(histr, sel, 0, thr);
    hist_pass<<<HBLK, 256, 0, stream>>>(ew, sel, 1, part);
    hist_reduce<<<HBINS / 256, 256, 0, stream>>>(part, histr);
    select_stage<<<1, 1024, 0, stream>>>(histr, sel, 1, thr);
    hist_pass<<<HBLK, 256, 0, stream>>>(ew, sel, 2, part);
    hist_reduce<<<HBINS / 256, 256, 0, stream>>>(part, histr);
    select_stage<<<1, 1024, 0, stream>>>(histr, sel, 2, thr);

    gemm1<<<(NN + 63) / 64, 256, 0, stream>>>(x, w1, hb);
    agg_relu1<<<NB4, 256, 0, stream>>>((const unsigned*)hb, dis, row_ptr, csr_src, b1, h1);
    gemm2<<<NB4, 256, 0, stream>>>(h1, w2, h2w);
    agg2_fused<<<NB4, 256, 0, stream>>>(h2w, dis, row_ptr, csr_src, b2, x2nw, out);
    loss_kernel<<<EB, 256, 0, stream>>>(srcv, dstv, ew, lu, x2nw, thr, accd);
    finalize<<<1, 1, 0, stream>>>(accd, out);
}

// Round 6
// 1172.487 us; speedup vs baseline: 2.9762x; 1.0684x over previous
//
#include <hip/hip_runtime.h>

#define NN 100000
#define NE 3200000
#define FIN 512
#define FH 64
#define FC 40
#define KRANK 1600000u   // E - int(E*0.5), 0-indexed ascending rank
#define HBLK 128         // blocks for hist passes (NE/HBLK = 25000 exactly)
#define HBINS 2048
#define NBUCK 391        // ceil(NN/256) buckets of 256 dst-nodes
#define BPAD 512
#define SBLK 250         // scatter blocks; NE/SBLK = 12800 exactly
#define EPB 12800

typedef __attribute__((ext_vector_type(8))) short bf16x8;   // 8 bf16 = 4 VGPRs
typedef __attribute__((ext_vector_type(4))) float f32x4;

// ---- raw bf16 pack/unpack (round-to-nearest-even) ----
__device__ __forceinline__ unsigned f2b_rn(float x) {
    unsigned u = __float_as_uint(x);
    return (u + 0x7FFFu + ((u >> 16) & 1u)) >> 16;
}
__device__ __forceinline__ unsigned pack2(float x, float y) {
    return f2b_rn(x) | (f2b_rn(y) << 16);
}
__device__ __forceinline__ float2 unp2(unsigned u) {
    return make_float2(__uint_as_float(u << 16), __uint_as_float(u & 0xFFFF0000u));
}

// ================= bucketed CSR construction =================
__global__ __launch_bounds__(256) void bucket_count(const int* __restrict__ dstv,
                                                    unsigned* __restrict__ bcnt) {
    __shared__ unsigned bh[4 * BPAD];
    int tid = threadIdx.x, wv = tid >> 6;
    for (int i = tid; i < 4 * BPAD; i += 256) bh[i] = 0u;
    __syncthreads();
    int base = blockIdx.x * EPB;
    for (int t = tid; t < EPB; t += 256) {
        int b = dstv[base + t] >> 8;
        atomicAdd(&bh[wv * BPAD + b], 1u);
    }
    __syncthreads();
    for (int i = tid; i < BPAD; i += 256) {
        unsigned s = bh[i] + bh[BPAD + i] + bh[2 * BPAD + i] + bh[3 * BPAD + i];
        if (s) atomicAdd(&bcnt[i], s);
    }
}

__global__ __launch_bounds__(512) void bucket_scan(const unsigned* __restrict__ bcnt,
                                                   unsigned* __restrict__ boff,
                                                   unsigned* __restrict__ bfill,
                                                   int* __restrict__ row_ptr) {
    __shared__ unsigned sc[512];
    int tid = threadIdx.x;
    unsigned v = (tid < NBUCK) ? bcnt[tid] : 0u;
    sc[tid] = v;
    __syncthreads();
    for (int off = 1; off < 512; off <<= 1) {
        unsigned t = (tid >= off) ? sc[tid - off] : 0u;
        __syncthreads();
        sc[tid] += t;
        __syncthreads();
    }
    unsigned excl = sc[tid] - v;
    boff[tid] = excl;
    bfill[tid] = excl;
    if (tid == 0) row_ptr[NN] = NE;
}

__global__ __launch_bounds__(256) void bucket_scatter(const int* __restrict__ srcv,
                                                      const int* __restrict__ dstv,
                                                      unsigned* __restrict__ bfill,
                                                      unsigned* __restrict__ bp) {
    __shared__ unsigned bh[4 * BPAD];
    __shared__ unsigned bbase[BPAD];
    __shared__ unsigned bfl[BPAD];
    int tid = threadIdx.x, wv = tid >> 6;
    for (int i = tid; i < 4 * BPAD; i += 256) bh[i] = 0u;
    __syncthreads();
    int base = blockIdx.x * EPB;
    for (int t = tid; t < EPB; t += 256) {
        int b = dstv[base + t] >> 8;
        atomicAdd(&bh[wv * BPAD + b], 1u);
    }
    __syncthreads();
    for (int i = tid; i < BPAD; i += 256) {
        unsigned s = bh[i] + bh[BPAD + i] + bh[2 * BPAD + i] + bh[3 * BPAD + i];
        bbase[i] = s ? atomicAdd(&bfill[i], s) : 0u;
        bfl[i] = 0u;
    }
    __syncthreads();
    for (int t = tid; t < EPB; t += 256) {
        int d = dstv[base + t];
        int b = d >> 8;
        unsigned r = atomicAdd(&bfl[b], 1u);
        unsigned pk = (unsigned)srcv[base + t] | ((unsigned)(d & 255) << 17);
        bp[bbase[b] + r] = pk;
    }
}

__global__ __launch_bounds__(256) void bucket_build(const unsigned* __restrict__ bp,
                                                    const unsigned* __restrict__ boff,
                                                    int* __restrict__ row_ptr,
                                                    float* __restrict__ dis,
                                                    int* __restrict__ csr_src) {
    __shared__ unsigned lh[4 * 256];
    __shared__ unsigned sc[256];
    __shared__ unsigned gbase[256];
    __shared__ unsigned fl2[256];
    int b = blockIdx.x, tid = threadIdx.x, wv = tid >> 6;
    unsigned e0 = boff[b], e1 = boff[b + 1];
    int ecnt = (int)(e1 - e0);
    for (int i = tid; i < 1024; i += 256) lh[i] = 0u;
    __syncthreads();
    for (int t = tid; t < ecnt; t += 256) {
        unsigned lid = bp[e0 + t] >> 17;
        atomicAdd(&lh[wv * 256 + lid], 1u);
    }
    __syncthreads();
    unsigned deg = lh[tid] + lh[256 + tid] + lh[512 + tid] + lh[768 + tid];
    sc[tid] = deg;
    __syncthreads();
    for (int off = 1; off < 256; off <<= 1) {
        unsigned t = (tid >= off) ? sc[tid - off] : 0u;
        __syncthreads();
        sc[tid] += t;
        __syncthreads();
    }
    unsigned excl = sc[tid] - deg;
    gbase[tid] = e0 + excl;
    fl2[tid] = 0u;
    int n = b * 256 + tid;
    if (n < NN) {
        row_ptr[n] = (int)(e0 + excl);
        dis[n] = rsqrtf((float)deg + 1.0f);
    }
    __syncthreads();
    for (int t = tid; t < ecnt; t += 256) {
        unsigned v = bp[e0 + t];
        unsigned lid = v >> 17;
        unsigned r = atomicAdd(&fl2[lid], 1u);
        csr_src[gbase[lid] + r] = (int)(v & 0x1FFFFu);
    }
}

// ================= threshold: 3-stage radix select =================
__global__ __launch_bounds__(256) void hist_pass(const float* __restrict__ ew,
                                                 const int* __restrict__ sel,
                                                 int stage,
                                                 unsigned* __restrict__ part) {
    __shared__ unsigned lh[4 * HBINS];
    int tid = threadIdx.x, blk = blockIdx.x;
    int wv = tid >> 6;
    for (int i = tid; i < 4 * HBINS; i += 256) lh[i] = 0u;
    __syncthreads();
    unsigned m1 = 0, m2 = 0;
    if (stage == 1) m1 = (unsigned)sel[0];
    if (stage == 2) m2 = ((unsigned)sel[0] << 11) | (unsigned)sel[2];
    int base = blk * (NE / HBLK);
    for (int t = tid; t < NE / HBLK; t += 256) {
        unsigned bits = __float_as_uint(ew[base + t]);
        if (stage == 0) {
            atomicAdd(&lh[wv * HBINS + (bits >> 21)], 1u);
        } else if (stage == 1) {
            if ((bits >> 21) == m1) atomicAdd(&lh[wv * HBINS + ((bits >> 10) & 0x7FFu)], 1u);
        } else {
            if ((bits >> 10) == m2) atomicAdd(&lh[wv * HBINS + (bits & 0x3FFu)], 1u);
        }
    }
    __syncthreads();
    for (int i = tid; i < HBINS; i += 256)
        part[blk * HBINS + i] = lh[i] + lh[HBINS + i] + lh[2 * HBINS + i] + lh[3 * HBINS + i];
}

__global__ __launch_bounds__(256) void hist_reduce(const unsigned* __restrict__ part,
                                                   unsigned* __restrict__ hist) {
    int bin = blockIdx.x * 256 + threadIdx.x;
    unsigned s = 0;
    for (int p = 0; p < HBLK; ++p) s += part[p * HBINS + bin];
    hist[bin] = s;
}

__global__ __launch_bounds__(1024) void select_stage(const unsigned* __restrict__ hist,
                                                     int* __restrict__ sel, int stage,
                                                     float* __restrict__ thr) {
    __shared__ unsigned sc[1024];
    __shared__ unsigned runs;
    int tid = threadIdx.x;
    unsigned Kr = (stage == 0) ? KRANK : (unsigned)sel[2 * stage - 1];
    if (tid == 0) runs = 0;
    __syncthreads();
    for (int ch = 0; ch < 2; ++ch) {
        unsigned v = hist[ch * 1024 + tid];
        sc[tid] = v;
        __syncthreads();
        for (int off = 1; off < 1024; off <<= 1) {
            unsigned t = (tid >= off) ? sc[tid - off] : 0u;
            __syncthreads();
            sc[tid] += t;
            __syncthreads();
        }
        unsigned incl = sc[tid];
        unsigned base = runs;
        unsigned lo = base + incl - v, hi = base + incl;
        if (Kr >= lo && Kr < hi) {
            int b = ch * 1024 + tid;
            sel[2 * stage] = b;
            sel[2 * stage + 1] = (int)(Kr - lo);
            if (stage == 2) {
                unsigned bits = ((unsigned)sel[0] << 21) | ((unsigned)sel[2] << 10) | (unsigned)b;
                thr[0] = __uint_as_float(bits);
            }
        }
        __syncthreads();
        if (tid == 1023) runs = base + incl;
        __syncthreads();
    }
}

// ===== GEMM1: h = x @ w1 via bf16 MFMA (fp32->bf16 on staging, fp32 acc) =====
// Block: 64 rows x 64 cols, 4 waves (wave w = rows w*16..w*16+15), K chunks of 32.
// LDS layout: u32 = bf16 k-pair; row stride 20 u32 (16B-aligned, bank-spread).
// Frag layouts (verified, guide §3): A[m=lane&15][k=quad*8+j], B[n=lane&15][k=quad*8+j],
// C: col=lane&15, row=quad*4+reg.
__global__ __launch_bounds__(256) void gemm1(const float* __restrict__ x,
                                             const float* __restrict__ w1,
                                             unsigned short* __restrict__ hb) {
    __shared__ unsigned sA[64 * 20];
    __shared__ unsigned sB[64 * 20];
    int tid = threadIdx.x;
    int wv = tid >> 6, lane = tid & 63;
    int quad = lane >> 4, l16 = lane & 15;
    int rowBase = blockIdx.x * 64;
    f32x4 acc[4] = {};
    for (int k0 = 0; k0 < FIN; k0 += 32) {
#pragma unroll
        for (int i = 0; i < 4; ++i) {
            int idx = tid + 256 * i;           // 1024 = 64 rows x 16 pairs
            int m = idx >> 4, kk = idx & 15;
            int gr = rowBase + m;
            float2 v = (gr < NN) ? *(const float2*)&x[(size_t)gr * FIN + k0 + 2 * kk]
                                 : make_float2(0.f, 0.f);
            sA[m * 20 + kk] = pack2(v.x, v.y);
        }
#pragma unroll
        for (int i = 0; i < 4; ++i) {
            int idx = tid + 256 * i;           // 1024 = 64 cols x 16 pairs
            int n = idx & 63, kk = idx >> 6;
            float a = w1[(size_t)(k0 + 2 * kk) * FH + n];
            float b = w1[(size_t)(k0 + 2 * kk + 1) * FH + n];
            sB[n * 20 + kk] = pack2(a, b);
        }
        __syncthreads();
        bf16x8 af = *(const bf16x8*)&sA[(wv * 16 + l16) * 20 + quad * 4];
#pragma unroll
        for (int c = 0; c < 4; ++c) {
            bf16x8 bfg = *(const bf16x8*)&sB[(c * 16 + l16) * 20 + quad * 4];
            acc[c] = __builtin_amdgcn_mfma_f32_16x16x32_bf16(af, bfg, acc[c], 0, 0, 0);
        }
        __syncthreads();
    }
#pragma unroll
    for (int r = 0; r < 4; ++r) {
        int row = rowBase + wv * 16 + quad * 4 + r;
        if (row < NN) {
#pragma unroll
            for (int c = 0; c < 4; ++c)
                hb[(size_t)row * FH + c * 16 + l16] = (unsigned short)f2b_rn(acc[c][r]);
        }
    }
}

// ================= aggregate layer 1 (+bias+relu), wave per node =================
__global__ __launch_bounds__(256) void agg_relu1(const unsigned* __restrict__ hb,
                                                 const float* __restrict__ dis,
                                                 const int* __restrict__ row_ptr,
                                                 const int* __restrict__ csr_src,
                                                 const float* __restrict__ b1,
                                                 float* __restrict__ h1) {
    int wave = threadIdx.x >> 6, lane = threadIdx.x & 63;
    int n = blockIdx.x * 4 + wave;
    if (n >= NN) return;
    int half = lane >> 5, li = lane & 31;
    float dn = dis[n];
    float2 acc = make_float2(0.f, 0.f);
    if (half == 0) {
        float2 v = unp2(hb[(size_t)n * 32 + li]);
        float w = dn * dn;
        acc.x = v.x * w; acc.y = v.y * w;
    }
    int e0 = row_ptr[n], e1 = row_ptr[n + 1];
    int e = e0 + half;
    for (; e + 2 < e1; e += 4) {
        int s0 = csr_src[e], s1 = csr_src[e + 2];
        float w0 = dis[s0] * dn, w1w = dis[s1] * dn;
        float2 v0 = unp2(hb[(size_t)s0 * 32 + li]);
        float2 v1 = unp2(hb[(size_t)s1 * 32 + li]);
        acc.x = fmaf(v0.x, w0, acc.x); acc.y = fmaf(v0.y, w0, acc.y);
        acc.x = fmaf(v1.x, w1w, acc.x); acc.y = fmaf(v1.y, w1w, acc.y);
    }
    if (e < e1) {
        int s = csr_src[e];
        float w = dis[s] * dn;
        float2 v = unp2(hb[(size_t)s * 32 + li]);
        acc.x = fmaf(v.x, w, acc.x); acc.y = fmaf(v.y, w, acc.y);
    }
    float ax = acc.x + __shfl_xor(acc.x, 32);
    float ay = acc.y + __shfl_xor(acc.y, 32);
    if (half == 0) {
        float2 b = ((const float2*)b1)[li];
        float2 o = make_float2(fmaxf(ax + b.x, 0.f), fmaxf(ay + b.y, 0.f));
        *(float2*)&h1[(size_t)n * FH + 2 * li] = o;
    }
}

// ================= GEMM2: h2 = h1 @ w2, bf16 store (20 words/row) =================
__global__ __launch_bounds__(256) void gemm2(const float* __restrict__ h1,
                                             const float* __restrict__ w2,
                                             unsigned* __restrict__ h2w) {
    __shared__ float w2s[FH * FC];
    int tid = threadIdx.x;
    for (int i = tid; i < FH * FC; i += 256) w2s[i] = w2[i];
    __syncthreads();
    int wave = tid >> 6, lane = tid & 63;
    int n = blockIdx.x * 4 + wave;
    if (n >= NN) return;
    float hv = h1[(size_t)n * FH + lane];
    int cl = (lane < FC) ? lane : 0;
    float acc = 0.f;
#pragma unroll
    for (int k = 0; k < FH; ++k) {
        float xk = __shfl(hv, k);
        acc = fmaf(xk, w2s[k * FC + cl], acc);
    }
    float lo = __shfl(acc, 2 * lane);
    float hi = __shfl(acc, 2 * lane + 1);
    if (lane < 20) h2w[(size_t)n * 20 + lane] = pack2(lo, hi);
}

// ============ aggregate layer 2 + bias + log_softmax + normalized bf16 x2 ============
__global__ __launch_bounds__(256) void agg2_fused(const unsigned* __restrict__ h2w,
                                                  const float* __restrict__ dis,
                                                  const int* __restrict__ row_ptr,
                                                  const int* __restrict__ csr_src,
                                                  const float* __restrict__ b2,
                                                  unsigned* __restrict__ x2nw,
                                                  float* __restrict__ outls) {
    int wave = threadIdx.x >> 6, lane = threadIdx.x & 63;
    int n = blockIdx.x * 4 + wave;
    if (n >= NN) return;
    int half = lane >> 5, li = lane & 31;
    bool ld = li < 20;
    int lidx = ld ? li : 19;
    float dn = dis[n];
    float2 acc = make_float2(0.f, 0.f);
    if (half == 0 && ld) {
        float2 v = unp2(h2w[(size_t)n * 20 + li]);
        float w = dn * dn;
        acc.x = v.x * w; acc.y = v.y * w;
    }
    int e0 = row_ptr[n], e1 = row_ptr[n + 1];
    int e = e0 + half;
    for (; e + 2 < e1; e += 4) {
        int s0 = csr_src[e], s1 = csr_src[e + 2];
        float w0 = dis[s0] * dn, w1w = dis[s1] * dn;
        float2 v0 = unp2(h2w[(size_t)s0 * 20 + lidx]);
        float2 v1 = unp2(h2w[(size_t)s1 * 20 + lidx]);
        if (ld) {
            acc.x = fmaf(v0.x, w0, acc.x); acc.y = fmaf(v0.y, w0, acc.y);
            acc.x = fmaf(v1.x, w1w, acc.x); acc.y = fmaf(v1.y, w1w, acc.y);
        }
    }
    if (e < e1) {
        int s = csr_src[e];
        float w = dis[s] * dn;
        float2 v = unp2(h2w[(size_t)s * 20 + lidx]);
        if (ld) { acc.x = fmaf(v.x, w, acc.x); acc.y = fmaf(v.y, w, acc.y); }
    }
    float ax = acc.x + __shfl_xor(acc.x, 32);
    float ay = acc.y + __shfl_xor(acc.y, 32);
    bool actv = (half == 0) && ld;
    float2 x2v;
    if (actv) {
        float2 b = ((const float2*)b2)[li];
        x2v = make_float2(ax + b.x, ay + b.y);
    } else {
        x2v = make_float2(-3.4e38f, -3.4e38f);
    }
    float m = fmaxf(x2v.x, x2v.y);
#pragma unroll
    for (int off = 16; off; off >>= 1) m = fmaxf(m, __shfl_xor(m, off));
    float ex = actv ? (expf(x2v.x - m) + expf(x2v.y - m)) : 0.f;
    float sq = actv ? (x2v.x * x2v.x + x2v.y * x2v.y) : 0.f;
#pragma unroll
    for (int off = 16; off; off >>= 1) {
        ex += __shfl_xor(ex, off);
        sq += __shfl_xor(sq, off);
    }
    if (actv) {
        float lse = m + logf(ex);
        *(float2*)&outls[(size_t)n * FC + 2 * li] = make_float2(x2v.x - lse, x2v.y - lse);
        float inv = 1.f / fmaxf(sqrtf(sq), 1e-8f);
        x2nw[(size_t)n * 20 + li] = pack2(x2v.x * inv, x2v.y * inv);
    }
}

// ================= edge loss: cos = dot of pre-normalized bf16 rows =================
__global__ __launch_bounds__(256) void loss_kernel(const int* __restrict__ srcv,
                                                   const int* __restrict__ dstv,
                                                   const float* __restrict__ ew,
                                                   const float* __restrict__ lu,
                                                   const unsigned* __restrict__ x2nw,
                                                   const float* __restrict__ thr,
                                                   double* __restrict__ acc) {
    int e = blockIdx.x * 256 + threadIdx.x;
    float term = 0.f;
    if (e < NE) {
        int s = srcv[e], d = dstv[e];
        const uint4* pa = (const uint4*)(x2nw + (size_t)s * 20);
        const uint4* pb = (const uint4*)(x2nw + (size_t)d * 20);
        float dot = 0.f;
#pragma unroll
        for (int i = 0; i < 5; ++i) {
            uint4 av = pa[i], bv = pb[i];
            float2 a0 = unp2(av.x), b0 = unp2(bv.x);
            float2 a1 = unp2(av.y), b1v = unp2(bv.y);
            float2 a2 = unp2(av.z), b2v = unp2(bv.z);
            float2 a3 = unp2(av.w), b3 = unp2(bv.w);
            dot += a0.x * b0.x + a0.y * b0.y + a1.x * b1v.x + a1.y * b1v.y
                 + a2.x * b2v.x + a2.y * b2v.y + a3.x * b3.x + a3.y * b3.y;
        }
        float cs = 1.f - dot;
        float w = ew[e];
        bool mk = (w >= thr[0]);
        float lp = mk ? cs : 1.f - cs;
        float le = mk ? w : 1.f - w;
        term = le * lp * lu[e];
    }
#pragma unroll
    for (int off = 32; off; off >>= 1) term += __shfl_down(term, off);
    __shared__ float ws4[4];
    int lane = threadIdx.x & 63, wid = threadIdx.x >> 6;
    if (lane == 0) ws4[wid] = term;
    __syncthreads();
    if (threadIdx.x == 0) {
        double s = (double)ws4[0] + (double)ws4[1] + (double)ws4[2] + (double)ws4[3];
        atomicAdd(acc, s);
    }
}

__global__ void finalize(const double* __restrict__ acc, float* __restrict__ out) {
    out[NN * FC] = (float)(acc[0] * (1.0 / (double)NE));
}

// ================= host launch =================
extern "C" void kernel_launch(void* const* d_in, const int* in_sizes, int n_in,
                              void* d_out, int out_size, void* d_ws, size_t ws_size,
                              hipStream_t stream) {
    const float* x  = (const float*)d_in[0];
    const int*   ei = (const int*)d_in[1];
    const float* ew = (const float*)d_in[2];
    const float* lu = (const float*)d_in[3];
    const float* w1 = (const float*)d_in[4];
    const float* b1 = (const float*)d_in[5];
    const float* w2 = (const float*)d_in[6];
    const float* b2 = (const float*)d_in[7];
    float* out = (float*)d_out;
    const int* srcv = ei;
    const int* dstv = ei + NE;

    char* ws = (char*)d_ws;
    size_t off = 0;
    auto alloc = [&](size_t bytes) -> void* {
        void* p = ws + off;
        off += (bytes + 255) & ~(size_t)255;
        return p;
    };
    float*    dis     = (float*)alloc((size_t)NN * 4);
    int*      row_ptr = (int*)alloc((size_t)(NN + 1) * 4);
    int*      csr_src = (int*)alloc((size_t)NE * 4);
    unsigned* bp      = (unsigned*)alloc((size_t)NE * 4);
    unsigned* bcnt    = (unsigned*)alloc((size_t)BPAD * 4);
    unsigned* boff2   = (unsigned*)alloc((size_t)BPAD * 4);
    unsigned* bfill   = (unsigned*)alloc((size_t)BPAD * 4);
    unsigned short* hb = (unsigned short*)alloc((size_t)NN * FH * 2);
    float*    h1      = (float*)alloc((size_t)NN * FH * 4);
    unsigned* h2w     = (unsigned*)alloc((size_t)NN * 20 * 4);
    unsigned* x2nw    = (unsigned*)alloc((size_t)NN * 20 * 4);
    unsigned* part    = (unsigned*)alloc((size_t)HBLK * HBINS * 4);
    unsigned* histr   = (unsigned*)alloc((size_t)HBINS * 4);
    int*      sel     = (int*)alloc(256);
    float*    thr     = (float*)alloc(256);
    double*   accd    = (double*)alloc(256);

    hipMemsetAsync(bcnt, 0, (size_t)BPAD * 4, stream);
    hipMemsetAsync(accd, 0, 8, stream);

    const int EB = (NE + 255) / 256;      // 12500
    const int NB4 = (NN + 3) / 4;         // 25000

    bucket_count<<<SBLK, 256, 0, stream>>>(dstv, bcnt);
    bucket_scan<<<1, 512, 0, stream>>>(bcnt, boff2, bfill, row_ptr);
    bucket_scatter<<<SBLK, 256, 0, stream>>>(srcv, dstv, bfill, bp);
    bucket_build<<<NBUCK, 256, 0, stream>>>(bp, boff2, row_ptr, dis, csr_src);

    hist_pass<<<HBLK, 256, 0, stream>>>(ew, sel, 0, part);
    hist_reduce<<<HBINS / 256, 256, 0, stream>>>(part, histr);
    select_stage<<<1, 1024, 0, stream>>>(histr, sel, 0, thr);
    hist_pass<<<HBLK, 256, 0, stream>>>(ew, sel, 1, part);
    hist_reduce<<<HBINS / 256, 256, 0, stream>>>(part, histr);
    select_stage<<<1, 1024, 0, stream>>>(histr, sel, 1, thr);
    hist_pass<<<HBLK, 256, 0, stream>>>(ew, sel, 2, part);
    hist_reduce<<<HBINS / 256, 256, 0, stream>>>(part, histr);
    select_stage<<<1, 1024, 0, stream>>>(histr, sel, 2, thr);

    gemm1<<<(NN + 63) / 64, 256, 0, stream>>>(x, w1, hb);
    agg_relu1<<<NB4, 256, 0, stream>>>((const unsigned*)hb, dis, row_ptr, csr_src, b1, h1);
    gemm2<<<NB4, 256, 0, stream>>>(h1, w2, h2w);
    agg2_fused<<<NB4, 256, 0, stream>>>(h2w, dis, row_ptr, csr_src, b2, x2nw, out);
    loss_kernel<<<EB, 256, 0, stream>>>(srcv, dstv, ew, lu, x2nw, thr, accd);
    finalize<<<1, 1, 0, stream>>>(accd, out);
}

// Round 7
// 1160.647 us; speedup vs baseline: 3.0066x; 1.0102x over previous
//
#include <hip/hip_runtime.h>

#define NN 100000
#define NE 3200000
#define FIN 512
#define FH 64
#define FC 40
#define KRANK 1600000u   // E - int(E*0.5), 0-indexed ascending rank
#define HBLK 128         // blocks for hist passes (NE/HBLK = 25000 exactly)
#define HBINS 2048
#define NBUCK 391        // ceil(NN/256) buckets of 256 dst-nodes
#define BPAD 512
#define SBLK 250         // scatter blocks; NE/SBLK = 12800 exactly
#define EPB 12800

typedef __attribute__((ext_vector_type(8))) short bf16x8;   // 8 bf16 = 4 VGPRs
typedef __attribute__((ext_vector_type(4))) float f32x4;

// ---- raw bf16 pack/unpack (round-to-nearest-even) ----
__device__ __forceinline__ unsigned f2b_rn(float x) {
    unsigned u = __float_as_uint(x);
    return (u + 0x7FFFu + ((u >> 16) & 1u)) >> 16;
}
__device__ __forceinline__ unsigned pack2(float x, float y) {
    return f2b_rn(x) | (f2b_rn(y) << 16);
}
__device__ __forceinline__ float2 unp2(unsigned u) {
    return make_float2(__uint_as_float(u << 16), __uint_as_float(u & 0xFFFF0000u));
}
// signed-int8 dot of packed words (compiler may fuse to v_dot4)
__device__ __forceinline__ int dot4i8(unsigned a, unsigned b, int c) {
    c += ((int)(a << 24) >> 24) * ((int)(b << 24) >> 24);
    c += ((int)(a << 16) >> 24) * ((int)(b << 16) >> 24);
    c += ((int)(a << 8) >> 24) * ((int)(b << 8) >> 24);
    c += ((int)a >> 24) * ((int)b >> 24);
    return c;
}

// ================= bucketed CSR construction =================
__global__ __launch_bounds__(256) void bucket_count(const int* __restrict__ dstv,
                                                    unsigned* __restrict__ bcnt) {
    __shared__ unsigned bh[4 * BPAD];
    int tid = threadIdx.x, wv = tid >> 6;
    for (int i = tid; i < 4 * BPAD; i += 256) bh[i] = 0u;
    __syncthreads();
    int base = blockIdx.x * EPB;
    for (int t = tid; t < EPB; t += 256) {
        int b = dstv[base + t] >> 8;
        atomicAdd(&bh[wv * BPAD + b], 1u);
    }
    __syncthreads();
    for (int i = tid; i < BPAD; i += 256) {
        unsigned s = bh[i] + bh[BPAD + i] + bh[2 * BPAD + i] + bh[3 * BPAD + i];
        if (s) atomicAdd(&bcnt[i], s);
    }
}

__global__ __launch_bounds__(512) void bucket_scan(const unsigned* __restrict__ bcnt,
                                                   unsigned* __restrict__ boff,
                                                   unsigned* __restrict__ bfill,
                                                   int* __restrict__ row_ptr) {
    __shared__ unsigned sc[512];
    int tid = threadIdx.x;
    unsigned v = (tid < NBUCK) ? bcnt[tid] : 0u;
    sc[tid] = v;
    __syncthreads();
    for (int off = 1; off < 512; off <<= 1) {
        unsigned t = (tid >= off) ? sc[tid - off] : 0u;
        __syncthreads();
        sc[tid] += t;
        __syncthreads();
    }
    unsigned excl = sc[tid] - v;
    boff[tid] = excl;
    bfill[tid] = excl;
    if (tid == 0) row_ptr[NN] = NE;
}

__global__ __launch_bounds__(256) void bucket_scatter(const int* __restrict__ srcv,
                                                      const int* __restrict__ dstv,
                                                      unsigned* __restrict__ bfill,
                                                      unsigned* __restrict__ bp) {
    __shared__ unsigned bh[4 * BPAD];
    __shared__ unsigned bbase[BPAD];
    __shared__ unsigned bfl[BPAD];
    int tid = threadIdx.x, wv = tid >> 6;
    for (int i = tid; i < 4 * BPAD; i += 256) bh[i] = 0u;
    __syncthreads();
    int base = blockIdx.x * EPB;
    for (int t = tid; t < EPB; t += 256) {
        int b = dstv[base + t] >> 8;
        atomicAdd(&bh[wv * BPAD + b], 1u);
    }
    __syncthreads();
    for (int i = tid; i < BPAD; i += 256) {
        unsigned s = bh[i] + bh[BPAD + i] + bh[2 * BPAD + i] + bh[3 * BPAD + i];
        bbase[i] = s ? atomicAdd(&bfill[i], s) : 0u;
        bfl[i] = 0u;
    }
    __syncthreads();
    for (int t = tid; t < EPB; t += 256) {
        int d = dstv[base + t];
        int b = d >> 8;
        unsigned r = atomicAdd(&bfl[b], 1u);
        unsigned pk = (unsigned)srcv[base + t] | ((unsigned)(d & 255) << 17);
        bp[bbase[b] + r] = pk;
    }
}

__global__ __launch_bounds__(256) void bucket_build(const unsigned* __restrict__ bp,
                                                    const unsigned* __restrict__ boff,
                                                    int* __restrict__ row_ptr,
                                                    float* __restrict__ dis,
                                                    int* __restrict__ csr_src) {
    __shared__ unsigned lh[4 * 256];
    __shared__ unsigned sc[256];
    __shared__ unsigned gbase[256];
    __shared__ unsigned fl2[256];
    int b = blockIdx.x, tid = threadIdx.x, wv = tid >> 6;
    unsigned e0 = boff[b], e1 = boff[b + 1];
    int ecnt = (int)(e1 - e0);
    for (int i = tid; i < 1024; i += 256) lh[i] = 0u;
    __syncthreads();
    for (int t = tid; t < ecnt; t += 256) {
        unsigned lid = bp[e0 + t] >> 17;
        atomicAdd(&lh[wv * 256 + lid], 1u);
    }
    __syncthreads();
    unsigned deg = lh[tid] + lh[256 + tid] + lh[512 + tid] + lh[768 + tid];
    sc[tid] = deg;
    __syncthreads();
    for (int off = 1; off < 256; off <<= 1) {
        unsigned t = (tid >= off) ? sc[tid - off] : 0u;
        __syncthreads();
        sc[tid] += t;
        __syncthreads();
    }
    unsigned excl = sc[tid] - deg;
    gbase[tid] = e0 + excl;
    fl2[tid] = 0u;
    int n = b * 256 + tid;
    if (n < NN) {
        row_ptr[n] = (int)(e0 + excl);
        dis[n] = rsqrtf((float)deg + 1.0f);
    }
    __syncthreads();
    for (int t = tid; t < ecnt; t += 256) {
        unsigned v = bp[e0 + t];
        unsigned lid = v >> 17;
        unsigned r = atomicAdd(&fl2[lid], 1u);
        csr_src[gbase[lid] + r] = (int)(v & 0x1FFFFu);
    }
}

// ================= threshold: 3-stage radix select =================
__global__ __launch_bounds__(256) void hist_pass(const float* __restrict__ ew,
                                                 const int* __restrict__ sel,
                                                 int stage,
                                                 unsigned* __restrict__ part) {
    __shared__ unsigned lh[4 * HBINS];
    int tid = threadIdx.x, blk = blockIdx.x;
    int wv = tid >> 6;
    for (int i = tid; i < 4 * HBINS; i += 256) lh[i] = 0u;
    __syncthreads();
    unsigned m1 = 0, m2 = 0;
    if (stage == 1) m1 = (unsigned)sel[0];
    if (stage == 2) m2 = ((unsigned)sel[0] << 11) | (unsigned)sel[2];
    int base = blk * (NE / HBLK);
    for (int t = tid; t < NE / HBLK; t += 256) {
        unsigned bits = __float_as_uint(ew[base + t]);
        if (stage == 0) {
            atomicAdd(&lh[wv * HBINS + (bits >> 21)], 1u);
        } else if (stage == 1) {
            if ((bits >> 21) == m1) atomicAdd(&lh[wv * HBINS + ((bits >> 10) & 0x7FFu)], 1u);
        } else {
            if ((bits >> 10) == m2) atomicAdd(&lh[wv * HBINS + (bits & 0x3FFu)], 1u);
        }
    }
    __syncthreads();
    for (int i = tid; i < HBINS; i += 256)
        part[blk * HBINS + i] = lh[i] + lh[HBINS + i] + lh[2 * HBINS + i] + lh[3 * HBINS + i];
}

__global__ __launch_bounds__(256) void hist_reduce(const unsigned* __restrict__ part,
                                                   unsigned* __restrict__ hist) {
    int bin = blockIdx.x * 256 + threadIdx.x;
    unsigned s = 0;
    for (int p = 0; p < HBLK; ++p) s += part[p * HBINS + bin];
    hist[bin] = s;
}

__global__ __launch_bounds__(1024) void select_stage(const unsigned* __restrict__ hist,
                                                     int* __restrict__ sel, int stage,
                                                     float* __restrict__ thr) {
    __shared__ unsigned sc[1024];
    __shared__ unsigned runs;
    int tid = threadIdx.x;
    unsigned Kr = (stage == 0) ? KRANK : (unsigned)sel[2 * stage - 1];
    if (tid == 0) runs = 0;
    __syncthreads();
    for (int ch = 0; ch < 2; ++ch) {
        unsigned v = hist[ch * 1024 + tid];
        sc[tid] = v;
        __syncthreads();
        for (int off = 1; off < 1024; off <<= 1) {
            unsigned t = (tid >= off) ? sc[tid - off] : 0u;
            __syncthreads();
            sc[tid] += t;
            __syncthreads();
        }
        unsigned incl = sc[tid];
        unsigned base = runs;
        unsigned lo = base + incl - v, hi = base + incl;
        if (Kr >= lo && Kr < hi) {
            int b = ch * 1024 + tid;
            sel[2 * stage] = b;
            sel[2 * stage + 1] = (int)(Kr - lo);
            if (stage == 2) {
                unsigned bits = ((unsigned)sel[0] << 21) | ((unsigned)sel[2] << 10) | (unsigned)b;
                thr[0] = __uint_as_float(bits);
            }
        }
        __syncthreads();
        if (tid == 1023) runs = base + incl;
        __syncthreads();
    }
}

// ===== GEMM1: h = x @ w1 via bf16 MFMA (fp32->bf16 on staging, fp32 acc) =====
__global__ __launch_bounds__(256) void gemm1(const float* __restrict__ x,
                                             const float* __restrict__ w1,
                                             unsigned short* __restrict__ hb) {
    __shared__ unsigned sA[64 * 20];
    __shared__ unsigned sB[64 * 20];
    int tid = threadIdx.x;
    int wv = tid >> 6, lane = tid & 63;
    int quad = lane >> 4, l16 = lane & 15;
    int rowBase = blockIdx.x * 64;
    f32x4 acc[4] = {};
    for (int k0 = 0; k0 < FIN; k0 += 32) {
#pragma unroll
        for (int i = 0; i < 4; ++i) {
            int idx = tid + 256 * i;
            int m = idx >> 4, kk = idx & 15;
            int gr = rowBase + m;
            float2 v = (gr < NN) ? *(const float2*)&x[(size_t)gr * FIN + k0 + 2 * kk]
                                 : make_float2(0.f, 0.f);
            sA[m * 20 + kk] = pack2(v.x, v.y);
        }
#pragma unroll
        for (int i = 0; i < 4; ++i) {
            int idx = tid + 256 * i;
            int n = idx & 63, kk = idx >> 6;
            float a = w1[(size_t)(k0 + 2 * kk) * FH + n];
            float b = w1[(size_t)(k0 + 2 * kk + 1) * FH + n];
            sB[n * 20 + kk] = pack2(a, b);
        }
        __syncthreads();
        bf16x8 af = *(const bf16x8*)&sA[(wv * 16 + l16) * 20 + quad * 4];
#pragma unroll
        for (int c = 0; c < 4; ++c) {
            bf16x8 bfg = *(const bf16x8*)&sB[(c * 16 + l16) * 20 + quad * 4];
            acc[c] = __builtin_amdgcn_mfma_f32_16x16x32_bf16(af, bfg, acc[c], 0, 0, 0);
        }
        __syncthreads();
    }
#pragma unroll
    for (int r = 0; r < 4; ++r) {
        int row = rowBase + wv * 16 + quad * 4 + r;
        if (row < NN) {
#pragma unroll
            for (int c = 0; c < 4; ++c)
                hb[(size_t)row * FH + c * 16 + l16] = (unsigned short)f2b_rn(acc[c][r]);
        }
    }
}

// ================= aggregate layer 1 (+bias+relu), wave per node =================
__global__ __launch_bounds__(256) void agg_relu1(const unsigned* __restrict__ hb,
                                                 const float* __restrict__ dis,
                                                 const int* __restrict__ row_ptr,
                                                 const int* __restrict__ csr_src,
                                                 const float* __restrict__ b1,
                                                 float* __restrict__ h1) {
    int wave = threadIdx.x >> 6, lane = threadIdx.x & 63;
    int n = blockIdx.x * 4 + wave;
    if (n >= NN) return;
    int half = lane >> 5, li = lane & 31;
    float dn = dis[n];
    float2 acc = make_float2(0.f, 0.f);
    if (half == 0) {
        float2 v = unp2(hb[(size_t)n * 32 + li]);
        float w = dn * dn;
        acc.x = v.x * w; acc.y = v.y * w;
    }
    int e0 = row_ptr[n], e1 = row_ptr[n + 1];
    int e = e0 + half;
    for (; e + 2 < e1; e += 4) {
        int s0 = csr_src[e], s1 = csr_src[e + 2];
        float w0 = dis[s0] * dn, w1w = dis[s1] * dn;
        float2 v0 = unp2(hb[(size_t)s0 * 32 + li]);
        float2 v1 = unp2(hb[(size_t)s1 * 32 + li]);
        acc.x = fmaf(v0.x, w0, acc.x); acc.y = fmaf(v0.y, w0, acc.y);
        acc.x = fmaf(v1.x, w1w, acc.x); acc.y = fmaf(v1.y, w1w, acc.y);
    }
    if (e < e1) {
        int s = csr_src[e];
        float w = dis[s] * dn;
        float2 v = unp2(hb[(size_t)s * 32 + li]);
        acc.x = fmaf(v.x, w, acc.x); acc.y = fmaf(v.y, w, acc.y);
    }
    float ax = acc.x + __shfl_xor(acc.x, 32);
    float ay = acc.y + __shfl_xor(acc.y, 32);
    if (half == 0) {
        float2 b = ((const float2*)b1)[li];
        float2 o = make_float2(fmaxf(ax + b.x, 0.f), fmaxf(ay + b.y, 0.f));
        *(float2*)&h1[(size_t)n * FH + 2 * li] = o;
    }
}

// ================= GEMM2: h2 = h1 @ w2, bf16 store (20 words/row) =================
__global__ __launch_bounds__(256) void gemm2(const float* __restrict__ h1,
                                             const float* __restrict__ w2,
                                             unsigned* __restrict__ h2w) {
    __shared__ float w2s[FH * FC];
    int tid = threadIdx.x;
    for (int i = tid; i < FH * FC; i += 256) w2s[i] = w2[i];
    __syncthreads();
    int wave = tid >> 6, lane = tid & 63;
    int n = blockIdx.x * 4 + wave;
    if (n >= NN) return;
    float hv = h1[(size_t)n * FH + lane];
    int cl = (lane < FC) ? lane : 0;
    float acc = 0.f;
#pragma unroll
    for (int k = 0; k < FH; ++k) {
        float xk = __shfl(hv, k);
        acc = fmaf(xk, w2s[k * FC + cl], acc);
    }
    float lo = __shfl(acc, 2 * lane);
    float hi = __shfl(acc, 2 * lane + 1);
    if (lane < 20) h2w[(size_t)n * 20 + lane] = pack2(lo, hi);
}

// ==== aggregate layer 2 + bias + log_softmax + int8-normalized x2 (48 B rows) ====
__global__ __launch_bounds__(256) void agg2_fused(const unsigned* __restrict__ h2w,
                                                  const float* __restrict__ dis,
                                                  const int* __restrict__ row_ptr,
                                                  const int* __restrict__ csr_src,
                                                  const float* __restrict__ b2,
                                                  unsigned* __restrict__ x2b,
                                                  float* __restrict__ outls) {
    int wave = threadIdx.x >> 6, lane = threadIdx.x & 63;
    int n = blockIdx.x * 4 + wave;
    if (n >= NN) return;
    int half = lane >> 5, li = lane & 31;
    bool ld = li < 20;
    int lidx = ld ? li : 19;
    float dn = dis[n];
    float2 acc = make_float2(0.f, 0.f);
    if (half == 0 && ld) {
        float2 v = unp2(h2w[(size_t)n * 20 + li]);
        float w = dn * dn;
        acc.x = v.x * w; acc.y = v.y * w;
    }
    int e0 = row_ptr[n], e1 = row_ptr[n + 1];
    int e = e0 + half;
    for (; e + 2 < e1; e += 4) {
        int s0 = csr_src[e], s1 = csr_src[e + 2];
        float w0 = dis[s0] * dn, w1w = dis[s1] * dn;
        float2 v0 = unp2(h2w[(size_t)s0 * 20 + lidx]);
        float2 v1 = unp2(h2w[(size_t)s1 * 20 + lidx]);
        if (ld) {
            acc.x = fmaf(v0.x, w0, acc.x); acc.y = fmaf(v0.y, w0, acc.y);
            acc.x = fmaf(v1.x, w1w, acc.x); acc.y = fmaf(v1.y, w1w, acc.y);
        }
    }
    if (e < e1) {
        int s = csr_src[e];
        float w = dis[s] * dn;
        float2 v = unp2(h2w[(size_t)s * 20 + lidx]);
        if (ld) { acc.x = fmaf(v.x, w, acc.x); acc.y = fmaf(v.y, w, acc.y); }
    }
    float ax = acc.x + __shfl_xor(acc.x, 32);
    float ay = acc.y + __shfl_xor(acc.y, 32);
    bool actv = (half == 0) && ld;
    float2 x2v;
    if (actv) {
        float2 b = ((const float2*)b2)[li];
        x2v = make_float2(ax + b.x, ay + b.y);
    } else {
        x2v = make_float2(-3.4e38f, -3.4e38f);
    }
    float m = fmaxf(x2v.x, x2v.y);
#pragma unroll
    for (int off = 16; off; off >>= 1) m = fmaxf(m, __shfl_xor(m, off));
    float ex = actv ? (expf(x2v.x - m) + expf(x2v.y - m)) : 0.f;
    float sq = actv ? (x2v.x * x2v.x + x2v.y * x2v.y) : 0.f;
#pragma unroll
    for (int off = 16; off; off >>= 1) {
        ex += __shfl_xor(ex, off);
        sq += __shfl_xor(sq, off);
    }
    // int8 quantize normalized row: q = round(v/||v|| * 127), clamp [-127,127]
    unsigned pk = 0;
    float inv = 0.f;
    if (actv) {
        inv = 127.f / fmaxf(sqrtf(sq), 1e-8f);
        int qx = (int)rintf(fminf(fmaxf(x2v.x * inv, -127.f), 127.f));
        int qy = (int)rintf(fminf(fmaxf(x2v.y * inv, -127.f), 127.f));
        pk = (unsigned)(qx & 0xFF) | ((unsigned)(qy & 0xFF) << 8);
    }
    // full-wave shuffles: word j <- lanes 2j, 2j+1 (lanes >=20 contribute 0 pads)
    unsigned wlo = __shfl(pk, (2 * lane) & 63);
    unsigned whi = __shfl(pk, (2 * lane + 1) & 63);
    unsigned wrd = wlo | (whi << 16);
    if (lane < 12) x2b[(size_t)n * 12 + lane] = wrd;
    if (actv) {
        float lse = m + logf(ex);
        *(float2*)&outls[(size_t)n * FC + 2 * li] = make_float2(x2v.x - lse, x2v.y - lse);
    }
}

// ========= edge loss: cos = int8 dot of pre-normalized rows / 127^2 =========
__global__ __launch_bounds__(256) void loss_kernel(const int* __restrict__ srcv,
                                                   const int* __restrict__ dstv,
                                                   const float* __restrict__ ew,
                                                   const float* __restrict__ lu,
                                                   const unsigned* __restrict__ x2b,
                                                   const float* __restrict__ thr,
                                                   double* __restrict__ acc) {
    int e = blockIdx.x * 256 + threadIdx.x;
    float term = 0.f;
    if (e < NE) {
        int s = srcv[e], d = dstv[e];
        const uint4* pa = (const uint4*)(x2b + (size_t)s * 12);
        const uint4* pb = (const uint4*)(x2b + (size_t)d * 12);
        int dot = 0;
#pragma unroll
        for (int i = 0; i < 3; ++i) {
            uint4 av = pa[i], bv = pb[i];
            dot = dot4i8(av.x, bv.x, dot);
            dot = dot4i8(av.y, bv.y, dot);
            dot = dot4i8(av.z, bv.z, dot);
            dot = dot4i8(av.w, bv.w, dot);
        }
        float cosv = (float)dot * (1.0f / 16129.0f);
        float cs = 1.f - cosv;
        float w = ew[e];
        bool mk = (w >= thr[0]);
        float lp = mk ? cs : 1.f - cs;
        float le = mk ? w : 1.f - w;
        term = le * lp * lu[e];
    }
#pragma unroll
    for (int off = 32; off; off >>= 1) term += __shfl_down(term, off);
    __shared__ float ws4[4];
    int lane = threadIdx.x & 63, wid = threadIdx.x >> 6;
    if (lane == 0) ws4[wid] = term;
    __syncthreads();
    if (threadIdx.x == 0) {
        double s = (double)ws4[0] + (double)ws4[1] + (double)ws4[2] + (double)ws4[3];
        atomicAdd(acc, s);
    }
}

__global__ void finalize(const double* __restrict__ acc, float* __restrict__ out) {
    out[NN * FC] = (float)(acc[0] * (1.0 / (double)NE));
}

// ================= host launch =================
extern "C" void kernel_launch(void* const* d_in, const int* in_sizes, int n_in,
                              void* d_out, int out_size, void* d_ws, size_t ws_size,
                              hipStream_t stream) {
    const float* x  = (const float*)d_in[0];
    const int*   ei = (const int*)d_in[1];
    const float* ew = (const float*)d_in[2];
    const float* lu = (const float*)d_in[3];
    const float* w1 = (const float*)d_in[4];
    const float* b1 = (const float*)d_in[5];
    const float* w2 = (const float*)d_in[6];
    const float* b2 = (const float*)d_in[7];
    float* out = (float*)d_out;
    const int* srcv = ei;
    const int* dstv = ei + NE;

    char* ws = (char*)d_ws;
    size_t off = 0;
    auto alloc = [&](size_t bytes) -> void* {
        void* p = ws + off;
        off += (bytes + 255) & ~(size_t)255;
        return p;
    };
    float*    dis     = (float*)alloc((size_t)NN * 4);
    int*      row_ptr = (int*)alloc((size_t)(NN + 1) * 4);
    int*      csr_src = (int*)alloc((size_t)NE * 4);
    unsigned* bp      = (unsigned*)alloc((size_t)NE * 4);
    unsigned* bcnt    = (unsigned*)alloc((size_t)BPAD * 4);
    unsigned* boff2   = (unsigned*)alloc((size_t)BPAD * 4);
    unsigned* bfill   = (unsigned*)alloc((size_t)BPAD * 4);
    unsigned short* hb = (unsigned short*)alloc((size_t)NN * FH * 2);
    float*    h1      = (float*)alloc((size_t)NN * FH * 4);
    unsigned* h2w     = (unsigned*)alloc((size_t)NN * 20 * 4);
    unsigned* x2b     = (unsigned*)alloc((size_t)NN * 12 * 4);   // int8 rows, 48 B
    unsigned* part    = (unsigned*)alloc((size_t)HBLK * HBINS * 4);
    unsigned* histr   = (unsigned*)alloc((size_t)HBINS * 4);
    int*      sel     = (int*)alloc(256);
    float*    thr     = (float*)alloc(256);
    double*   accd    = (double*)alloc(256);

    hipMemsetAsync(bcnt, 0, (size_t)BPAD * 4, stream);
    hipMemsetAsync(accd, 0, 8, stream);

    const int EB = (NE + 255) / 256;      // 12500
    const int NB4 = (NN + 3) / 4;         // 25000

    bucket_count<<<SBLK, 256, 0, stream>>>(dstv, bcnt);
    bucket_scan<<<1, 512, 0, stream>>>(bcnt, boff2, bfill, row_ptr);
    bucket_scatter<<<SBLK, 256, 0, stream>>>(srcv, dstv, bfill, bp);
    bucket_build<<<NBUCK, 256, 0, stream>>>(bp, boff2, row_ptr, dis, csr_src);

    hist_pass<<<HBLK, 256, 0, stream>>>(ew, sel, 0, part);
    hist_reduce<<<HBINS / 256, 256, 0, stream>>>(part, histr);
    select_stage<<<1, 1024, 0, stream>>>(histr, sel, 0, thr);
    hist_pass<<<HBLK, 256, 0, stream>>>(ew, sel, 1, part);
    hist_reduce<<<HBINS / 256, 256, 0, stream>>>(part, histr);
    select_stage<<<1, 1024, 0, stream>>>(histr, sel, 1, thr);
    hist_pass<<<HBLK, 256, 0, stream>>>(ew, sel, 2, part);
    hist_reduce<<<HBINS / 256, 256, 0, stream>>>(part, histr);
    select_stage<<<1, 1024, 0, stream>>>(histr, sel, 2, thr);

    gemm1<<<(NN + 63) / 64, 256, 0, stream>>>(x, w1, hb);
    agg_relu1<<<NB4, 256, 0, stream>>>((const unsigned*)hb, dis, row_ptr, csr_src, b1, h1);
    gemm2<<<NB4, 256, 0, stream>>>(h1, w2, h2w);
    agg2_fused<<<NB4, 256, 0, stream>>>(h2w, dis, row_ptr, csr_src, b2, x2b, out);
    loss_kernel<<<EB, 256, 0, stream>>>(srcv, dstv, ew, lu, x2b, thr, accd);
    finalize<<<1, 1, 0, stream>>>(accd, out);
}